// Round 8
// baseline (184.381 us; speedup 1.0000x reference)
//
#include <hip/hip_runtime.h>
#include <hip/hip_bf16.h>
#include <cstdint>

#define BB 64
#define NN_ 500
#define NP 512
#define EE 128
#define NHEAD 8
#define HD 16

typedef float f32x4 __attribute__((ext_vector_type(4)));
typedef unsigned u32x4 __attribute__((ext_vector_type(4)));
typedef short s16x8 __attribute__((ext_vector_type(8)));
typedef short s16x4 __attribute__((ext_vector_type(4)));

__device__ __forceinline__ unsigned short f2bf(float f) {
  unsigned u = __builtin_bit_cast(unsigned, f);
  u += 0x7FFFu + ((u >> 16) & 1u);
  return (unsigned short)(u >> 16);
}

__device__ __forceinline__ float bf2f(unsigned short u) {
  unsigned v = ((unsigned)u) << 16;
  return __builtin_bit_cast(float, v);
}

__device__ __forceinline__ unsigned cvtpk(float a, float b) {
  unsigned r;
  asm("v_cvt_pk_bf16_f32 %0, %1, %2" : "=v"(r) : "v"(a), "v"(b));
  return r;
}

// cvtpk whose result feeds an MFMA operand: pad 2 wait-states inside the asm so the
// VALU-write -> MFMA-read distance is guaranteed independent of scheduling.
__device__ __forceinline__ unsigned cvtpk_m(float a, float b) {
  unsigned r;
  asm("v_cvt_pk_bf16_f32 %0, %1, %2\n\ts_nop 1" : "=v"(r) : "v"(a), "v"(b));
  return r;
}

__device__ __forceinline__ float EXP2(float x) {
  float r;
  asm("v_exp_f32 %0, %1" : "=v"(r) : "v"(x));
  return r;
}

__device__ __forceinline__ float RCP(float x) {
  float r;
  asm("v_rcp_f32 %0, %1" : "=v"(r) : "v"(x));
  return r;
}

__device__ __forceinline__ s16x8 pack8(f32x4 a, f32x4 b) {
  u32x4 u = { cvtpk(a[0], a[1]), cvtpk(a[2], a[3]), cvtpk(b[0], b[1]), cvtpk(b[2], b[3]) };
  return __builtin_bit_cast(s16x8, u);
}

__device__ __forceinline__ s16x8 pack8_m(f32x4 a, f32x4 b) {
  u32x4 u = { cvtpk_m(a[0], a[1]), cvtpk_m(a[2], a[3]), cvtpk_m(b[0], b[1]), cvtpk_m(b[2], b[3]) };
  return __builtin_bit_cast(s16x8, u);
}

__device__ __forceinline__ f32x4 MFMA(s16x8 a, s16x8 b, f32x4 c) {
  return __builtin_amdgcn_mfma_f32_16x16x32_bf16(a, b, c, 0, 0, 0);
}

// ---------------- K0b: W^T bf16; mats order [q1,q0,k,v,c], WT[m][n][k]=W[k][n] ----------------
__global__ void k_conv_w(const float* __restrict__ w0, const float* __restrict__ w1,
                         const float* __restrict__ w2, const float* __restrict__ w3,
                         const float* __restrict__ w4, unsigned short* __restrict__ wt) {
  int idx = blockIdx.x * 256 + threadIdx.x;   // 5*128*128 = 81920
  int k = idx & 127;
  int n = (idx >> 7) & 127;
  int m = idx >> 14;
  const float* w = (m == 0) ? w0 : (m == 1) ? w1 : (m == 2) ? w2 : (m == 3) ? w3 : w4;
  wt[idx] = f2bf(w[k * 128 + n]);
}

// ---------------- K1: projections -> QH, KH head-major [b][h][n][16], VT [b][h][16][n] ----------------
// ef f32->bf16 conversion fused in (was k_conv_ef): the A-fragments this block needs are
// exactly its own 32 rows; cw==0 waves write ef_bf (pad rows -> 0) for k_fused Phase C.
__global__ __launch_bounds__(256) void k_proj(
    const float* __restrict__ ef,
    const float* __restrict__ eq1, const float* __restrict__ eq0,
    const unsigned short* __restrict__ wt,
    unsigned short* __restrict__ qh, unsigned short* __restrict__ kh,
    unsigned short* __restrict__ vt_bf, unsigned short* __restrict__ ef_bf) {
  int wgid = blockIdx.x;                 // 1024
  int xcd = wgid & 7;
  int s = wgid >> 3;
  int nt = s & 15;
  int b = (s >> 4) * 8 + xcd;
  int tid = threadIdx.x;
  int w = tid >> 6, lane = tid & 63, g = lane >> 4, c = lane & 15;
  int rw = w & 1, cw = w >> 1;
  int nbase = nt * 32 + rw * 16;

  f32x4 ak[4], av[4], aq[4];
#pragma unroll
  for (int t = 0; t < 4; ++t) { ak[t]=(f32x4){0,0,0,0}; av[t]=(f32x4){0,0,0,0}; aq[t]=(f32x4){0,0,0,0}; }

  int nA = nbase + c;
  int nc = nA < NN_ ? nA : NN_ - 1;
  bool val = (nA < NN_);

  for (int kk = 0; kk < 4; ++kk) {
    int k0 = kk * 32 + 8 * g;
    const f32x4* pe = reinterpret_cast<const f32x4*>(ef + ((size_t)(b * NN_ + nc)) * EE + k0);
    s16x8 aef = {0,0,0,0,0,0,0,0};
    if (val) aef = pack8(pe[0], pe[1]);
    if (cw == 0)
      *reinterpret_cast<s16x8*>(ef_bf + ((size_t)(b * NP + nA)) * EE + k0) = aef;
    const f32x4* p1 = reinterpret_cast<const f32x4*>(eq1 + ((size_t)(b * NN_ + nc)) * EE + k0);
    const f32x4* p0 = reinterpret_cast<const f32x4*>(eq0 + ((size_t)(b * NN_ + nc)) * EE + k0);
    s16x8 a1 = pack8(p1[0], p1[1]);
    s16x8 a0 = pack8(p0[0], p0[1]);
#pragma unroll
    for (int tc = 0; tc < 4; ++tc) {
      int e = cw * 64 + tc * 16 + c;
      const unsigned short* wrow = wt + e * EE + k0;
      s16x8 bq1 = *reinterpret_cast<const s16x8*>(wrow);
      s16x8 bq0 = *reinterpret_cast<const s16x8*>(wrow + 1 * 16384);
      s16x8 bk  = *reinterpret_cast<const s16x8*>(wrow + 2 * 16384);
      s16x8 bv  = *reinterpret_cast<const s16x8*>(wrow + 3 * 16384);
      ak[tc] = MFMA(aef, bk, ak[tc]);
      av[tc] = MFMA(aef, bv, av[tc]);
      aq[tc] = MFMA(a1, bq1, aq[tc]);
      aq[tc] = MFMA(a0, bq0, aq[tc]);
    }
  }
#pragma unroll
  for (int tc = 0; tc < 4; ++tc) {
    int h = cw * 4 + tc;                 // e = cw*64+tc*16+c -> head, d = c
#pragma unroll
    for (int r = 0; r < 4; ++r) {
      int n = nbase + 4 * g + r;
      size_t off = ((size_t)((b * NHEAD + h) * NP) + n) * HD + c;
      kh[off] = f2bf(ak[tc][r]);         // padded rows: aef=0 -> ak=0, naturally safe
      qh[off] = f2bf(aq[tc][r]);         // padded rows garbage-but-finite; outputs unused
    }
    int n0 = nbase + 4 * g;
    unsigned pv0 = cvtpk(av[tc][0], av[tc][1]);
    unsigned pv1 = cvtpk(av[tc][2], av[tc][3]);
    *reinterpret_cast<uint2*>(vt_bf + (((size_t)(b * NHEAD + h)) * HD + c) * NP + n0) =
        make_uint2(pv0, pv1);
  }
}

// ---------------- K2: FUSED attn + combine + pointer-logits per (b, 32-row tile) ----------------
// 512 threads = 8 waves. Phase A: wave w owns head h=w completely, two sequential 16-row
// halves, PV in registers, zero Phase-A barriers. No max-subtraction (bounded scores; cols
// >=500 handled by selects producing mask' = -14427 -> exp2 -> exact 0).
// LDS 40448 B (smask[32][500] + sao[32][132], reds aliased on sao) -> 4 blocks/CU, whole
// grid co-resident.
__global__ __launch_bounds__(512, 4) void k_fused(
    const unsigned short* __restrict__ qh, const unsigned short* __restrict__ kh,
    const unsigned short* __restrict__ vt, const unsigned short* __restrict__ ef_bf,
    const unsigned short* __restrict__ wt, const float* __restrict__ bcp,
    const float* __restrict__ mask, float* __restrict__ probs) {
  int wgid = blockIdx.x;                 // 1024
  int xcd = wgid & 7;
  int s = wgid >> 3;
  int nt = s & 15;
  int b = (s >> 4) * 8 + xcd;            // all 16 tiles of b on one XCD
  int tid = threadIdx.x;
  int w = tid >> 6, lane = tid & 63, g = lane >> 4, c = lane & 15;
  int nt32 = nt * 32;

  __shared__ __align__(16) char uni[40448];
  unsigned short (*smask)[500] = reinterpret_cast<unsigned short(*)[500]>(uni);          // 32000 B
  unsigned short (*sao)[132]   = reinterpret_cast<unsigned short(*)[132]>(uni + 32000);  // 8448 B
  float (*reds)[2][16]         = reinterpret_cast<float(*)[2][16]>(uni + 32000);         // aliases sao

  const float LOG2E = 1.4426950408889634f;
  const unsigned short BFNI = f2bf(-14427.0f);

  // ---- stage mask' = log2e * mask as bf16, real 500 cols only ----
  for (int idx = tid; idx < 32 * 125; idx += 512) {
    int rl = idx / 125;
    int m4 = idx - rl * 125;
    int nr = nt32 + rl;
    f32x4 v = {0.f, 0.f, 0.f, 0.f};
    if (nr < NN_) v = *reinterpret_cast<const f32x4*>(mask + ((size_t)b * NN_ + nr) * NN_ + m4 * 4);
    unsigned lo = cvtpk(v[0] * LOG2E, v[1] * LOG2E);
    unsigned hi = cvtpk(v[2] * LOG2E, v[3] * LOG2E);
    *reinterpret_cast<uint2*>(&smask[rl][m4 * 4]) = make_uint2(lo, hi);
  }
  __syncthreads();                        // S1: smask visible

  // ================= Phase A: attention, wave w = head w, zero barriers =================
  {
    int h = w;
    const unsigned short* qb = qh + ((size_t)(b * NHEAD + h)) * NP * HD;
    const unsigned short* kb = kh + ((size_t)(b * NHEAD + h)) * NP * HD;
    const unsigned short* vrow = vt + (((size_t)(b * NHEAD + h)) * HD + c) * NP;

    for (int hf = 0; hf < 2; ++hf) {
      int ro = hf * 16;                  // n-row offset within tile
      s16x4 q4 = *reinterpret_cast<const s16x4*>(qb + (nt32 + ro + c) * HD + 4 * g);
      s16x8 bq = { q4[0], q4[1], q4[2], q4[3], 0, 0, 0, 0 };

      f32x4 o = {0, 0, 0, 0};
      float ls = 0.0f;
      for (int mt = 0; mt < 16; ++mt) {
        int m0 = mt * 32;
        s16x4 k40 = *reinterpret_cast<const s16x4*>(kb + (m0 + c) * HD + 4 * g);
        s16x4 k41 = *reinterpret_cast<const s16x4*>(kb + (m0 + 16 + c) * HD + 4 * g);
        s16x8 kf0 = { k40[0], k40[1], k40[2], k40[3], 0, 0, 0, 0 };
        s16x8 kf1 = { k41[0], k41[1], k41[2], k41[3], 0, 0, 0, 0 };
        s16x4 mk0 = *reinterpret_cast<const s16x4*>(&smask[ro + c][m0 + 4 * g]);
        s16x4 mk1;
        if (mt < 15 || g == 0)
          mk1 = *reinterpret_cast<const s16x4*>(&smask[ro + c][m0 + 16 + 4 * g]);
        else
          mk1 = (s16x4){ (short)BFNI, (short)BFNI, (short)BFNI, (short)BFNI };
        f32x4 a0 = MFMA(kf0, bq, (f32x4){0,0,0,0});
        f32x4 a1 = MFMA(kf1, bq, (f32x4){0,0,0,0});
#pragma unroll
        for (int j = 0; j < 4; ++j) {
          a0[j] = EXP2(fmaf(a0[j], 0.36067376022224085f, bf2f((unsigned short)mk0[j])));
          a1[j] = EXP2(fmaf(a1[j], 0.36067376022224085f, bf2f((unsigned short)mk1[j])));
          ls += a0[j] + a1[j];
        }
        s16x8 pa = pack8_m(a0, a1);      // s_nop-hardened: feeds MFMA SrcB
        s16x4 va = *reinterpret_cast<const s16x4*>(vrow + m0 + 4 * g);
        s16x4 v2 = *reinterpret_cast<const s16x4*>(vrow + m0 + 16 + 4 * g);
        s16x8 af = { va[0], va[1], va[2], va[3], v2[0], v2[1], v2[2], v2[3] };
        o = MFMA(af, pa, o);
      }
      ls += __shfl_xor(ls, 16);
      ls += __shfl_xor(ls, 32);
      float inv = RCP(ls);
      *reinterpret_cast<uint2*>(&sao[ro + c][w * HD + 4 * g]) =
          make_uint2(cvtpk(o[0] * inv, o[1] * inv), cvtpk(o[2] * inv, o[3] * inv));
    }
  }
  __syncthreads();                        // A1: sao (ao tile) complete

  // ================= Phase B: mh = ao @ Wc + bc =================
  int mw = w & 3, nw = w >> 2;
  float bias0 = bcp[mw * 32 + c];
  float bias1 = bcp[mw * 32 + 16 + c];
  f32x4 acm0 = {0,0,0,0}, acm1 = {0,0,0,0};
#pragma unroll
  for (int kk = 0; kk < 4; ++kk) {
    int k0 = kk * 32 + 8 * g;
    s16x8 aa = *reinterpret_cast<const s16x8*>(&sao[nw * 16 + c][k0]);
    s16x8 bw0 = *reinterpret_cast<const s16x8*>(wt + 4 * 16384 + (mw * 32 + c) * EE + k0);
    s16x8 bw1 = *reinterpret_cast<const s16x8*>(wt + 4 * 16384 + (mw * 32 + 16 + c) * EE + k0);
    acm0 = MFMA(aa, bw0, acm0);
    acm1 = MFMA(aa, bw1, acm1);
  }
  __syncthreads();                        // B1: all sao reads done
#pragma unroll
  for (int r = 0; r < 4; ++r) {
    sao[nw * 16 + 4 * g + r][mw * 32 + c]      = f2bf(acm0[r] + bias0);
    sao[nw * 16 + 4 * g + r][mw * 32 + 16 + c] = f2bf(acm1[r] + bias1);
  }
  __syncthreads();                        // B2: mh tile ready

  // ================= Phase C: pointer logits + softmax (no max-sub; tanh bounds) =====
  f32x4 sc[8];
#pragma unroll
  for (int t = 0; t < 8; ++t) sc[t] = (f32x4){0,0,0,0};
#pragma unroll
  for (int kk = 0; kk < 4; ++kk) {
    int k0 = kk * 32 + 8 * g;
    s16x8 am = *reinterpret_cast<const s16x8*>(&sao[nw * 16 + c][k0]);
#pragma unroll
    for (int t = 0; t < 8; ++t) {
      int m = mw * 128 + t * 16 + c;
      s16x8 bfr = *reinterpret_cast<const s16x8*>(ef_bf + ((size_t)(b * NP + m)) * EE + k0);
      sc[t] = MFMA(am, bfr, sc[t]);
    }
  }
  float rsum[4] = {0, 0, 0, 0};
#pragma unroll
  for (int t = 0; t < 8; ++t) {
    int m = mw * 128 + t * 16 + c;
    bool mok = (m < NN_);
#pragma unroll
    for (int r = 0; r < 4; ++r) {
      float x = sc[t][r] * 0.08838834764831845f;   // 1/sqrt(128)
      float ax = fabsf(x);
      float e2 = EXP2(ax * 2.8853900817779268f);   // e^(2|x|)
      float th = copysignf(1.0f - 2.0f * RCP(e2 + 1.0f), x);
      float mm = mok ? bf2f(smask[nw * 16 + 4 * g + r][m]) : -14427.0f;
      float p = EXP2(fmaf(th, 14.426950408889634f, mm));
      sc[t][r] = p;                                 // m>=500 -> p = 0
      rsum[r] += p;
    }
  }
#pragma unroll
  for (int r = 0; r < 4; ++r) {
    rsum[r] += __shfl_xor(rsum[r], 1);
    rsum[r] += __shfl_xor(rsum[r], 2);
    rsum[r] += __shfl_xor(rsum[r], 4);
    rsum[r] += __shfl_xor(rsum[r], 8);
  }
  __syncthreads();                        // C0: sao fully dead; reds may overwrite it
  if (c == 0) {
#pragma unroll
    for (int r = 0; r < 4; ++r) reds[mw][nw][4 * g + r] = rsum[r];
  }
  __syncthreads();                        // C1
  float inv[4];
#pragma unroll
  for (int r = 0; r < 4; ++r) {
    int rr = 4 * g + r;
    inv[r] = RCP(reds[0][nw][rr] + reds[1][nw][rr] + reds[2][nw][rr] + reds[3][nw][rr]);
  }
#pragma unroll
  for (int t = 0; t < 8; ++t) {
    int m = mw * 128 + t * 16 + c;
    if (m < NN_) {
#pragma unroll
      for (int r = 0; r < 4; ++r) {
        int ng = nt32 + nw * 16 + 4 * g + r;
        if (ng < NN_) probs[((size_t)b * NN_ + ng) * NN_ + m] = sc[t][r] * inv[r];
      }
    }
  }
}

extern "C" void kernel_launch(void* const* d_in, const int* in_sizes, int n_in,
                              void* d_out, int out_size, void* d_ws, size_t ws_size,
                              hipStream_t stream) {
  const float* ef   = (const float*)d_in[0];
  const float* eq1  = (const float*)d_in[1];
  const float* eq0  = (const float*)d_in[2];
  const float* mask = (const float*)d_in[3];
  const float* wq1  = (const float*)d_in[4];
  const float* wq0  = (const float*)d_in[5];
  const float* wk   = (const float*)d_in[6];
  const float* wv   = (const float*)d_in[7];
  const float* wc   = (const float*)d_in[8];
  const float* bc   = (const float*)d_in[9];
  float* probs = (float*)d_out;

  char* ws = (char*)d_ws;
  const size_t SL = 8388608;  // 64*512*128*2 bytes
  unsigned short* ef_bf = (unsigned short*)(ws);
  unsigned short* qh    = (unsigned short*)(ws + 1 * SL);
  unsigned short* kh    = (unsigned short*)(ws + 2 * SL);
  unsigned short* vt_bf = (unsigned short*)(ws + 3 * SL);
  unsigned short* wt    = (unsigned short*)(ws + 4 * SL);

  k_conv_w<<<320, 256, 0, stream>>>(wq1, wq0, wk, wv, wc, wt);
  k_proj<<<1024, 256, 0, stream>>>(ef, eq1, eq0, wt, qh, kh, vt_bf, ef_bf);
  k_fused<<<1024, 512, 0, stream>>>(qh, kh, vt_bf, ef_bf, wt, bc, mask, probs);
}

// Round 9
// 150.917 us; speedup vs baseline: 1.2217x; 1.2217x over previous
//
#include <hip/hip_runtime.h>
#include <hip/hip_bf16.h>
#include <cstdint>

#define BB 64
#define NN_ 500
#define NP 512
#define EE 128
#define NHEAD 8
#define HD 16

typedef float f32x4 __attribute__((ext_vector_type(4)));
typedef unsigned u32x4 __attribute__((ext_vector_type(4)));
typedef short s16x8 __attribute__((ext_vector_type(8)));
typedef short s16x4 __attribute__((ext_vector_type(4)));

__device__ __forceinline__ unsigned short f2bf(float f) {
  unsigned u = __builtin_bit_cast(unsigned, f);
  u += 0x7FFFu + ((u >> 16) & 1u);
  return (unsigned short)(u >> 16);
}

__device__ __forceinline__ float bf2f(unsigned short u) {
  unsigned v = ((unsigned)u) << 16;
  return __builtin_bit_cast(float, v);
}

__device__ __forceinline__ unsigned cvtpk(float a, float b) {
  unsigned r;
  asm("v_cvt_pk_bf16_f32 %0, %1, %2" : "=v"(r) : "v"(a), "v"(b));
  return r;
}

// cvtpk whose result feeds an MFMA operand: pad 2 wait-states inside the asm so the
// VALU-write -> MFMA-read distance is guaranteed independent of scheduling.
__device__ __forceinline__ unsigned cvtpk_m(float a, float b) {
  unsigned r;
  asm("v_cvt_pk_bf16_f32 %0, %1, %2\n\ts_nop 1" : "=v"(r) : "v"(a), "v"(b));
  return r;
}

__device__ __forceinline__ float EXP2(float x) {
  float r;
  asm("v_exp_f32 %0, %1" : "=v"(r) : "v"(x));
  return r;
}

__device__ __forceinline__ float RCP(float x) {
  float r;
  asm("v_rcp_f32 %0, %1" : "=v"(r) : "v"(x));
  return r;
}

__device__ __forceinline__ s16x8 pack8(f32x4 a, f32x4 b) {
  u32x4 u = { cvtpk(a[0], a[1]), cvtpk(a[2], a[3]), cvtpk(b[0], b[1]), cvtpk(b[2], b[3]) };
  return __builtin_bit_cast(s16x8, u);
}

__device__ __forceinline__ s16x8 pack8_m(f32x4 a, f32x4 b) {
  u32x4 u = { cvtpk_m(a[0], a[1]), cvtpk_m(a[2], a[3]), cvtpk_m(b[0], b[1]), cvtpk_m(b[2], b[3]) };
  return __builtin_bit_cast(s16x8, u);
}

__device__ __forceinline__ f32x4 MFMA(s16x8 a, s16x8 b, f32x4 c) {
  return __builtin_amdgcn_mfma_f32_16x16x32_bf16(a, b, c, 0, 0, 0);
}

// ---------------- K0b: W^T bf16; mats order [q1,q0,k,v,c], WT[m][n][k]=W[k][n] ----------------
__global__ void k_conv_w(const float* __restrict__ w0, const float* __restrict__ w1,
                         const float* __restrict__ w2, const float* __restrict__ w3,
                         const float* __restrict__ w4, unsigned short* __restrict__ wt) {
  int idx = blockIdx.x * 256 + threadIdx.x;   // 5*128*128 = 81920
  int k = idx & 127;
  int n = (idx >> 7) & 127;
  int m = idx >> 14;
  const float* w = (m == 0) ? w0 : (m == 1) ? w1 : (m == 2) ? w2 : (m == 3) ? w3 : w4;
  wt[idx] = f2bf(w[k * 128 + n]);
}

// ---------------- K1: projections -> QH, KH head-major [b][h][n][16], VT [b][h][16][n] ----------------
// ef f32->bf16 conversion fused in: cw==0 waves write ef_bf (pad rows -> 0) for k_fused Phase C.
__global__ __launch_bounds__(256) void k_proj(
    const float* __restrict__ ef,
    const float* __restrict__ eq1, const float* __restrict__ eq0,
    const unsigned short* __restrict__ wt,
    unsigned short* __restrict__ qh, unsigned short* __restrict__ kh,
    unsigned short* __restrict__ vt_bf, unsigned short* __restrict__ ef_bf) {
  int wgid = blockIdx.x;                 // 1024
  int xcd = wgid & 7;
  int s = wgid >> 3;
  int nt = s & 15;
  int b = (s >> 4) * 8 + xcd;
  int tid = threadIdx.x;
  int w = tid >> 6, lane = tid & 63, g = lane >> 4, c = lane & 15;
  int rw = w & 1, cw = w >> 1;
  int nbase = nt * 32 + rw * 16;

  f32x4 ak[4], av[4], aq[4];
#pragma unroll
  for (int t = 0; t < 4; ++t) { ak[t]=(f32x4){0,0,0,0}; av[t]=(f32x4){0,0,0,0}; aq[t]=(f32x4){0,0,0,0}; }

  int nA = nbase + c;
  int nc = nA < NN_ ? nA : NN_ - 1;
  bool val = (nA < NN_);

  for (int kk = 0; kk < 4; ++kk) {
    int k0 = kk * 32 + 8 * g;
    const f32x4* pe = reinterpret_cast<const f32x4*>(ef + ((size_t)(b * NN_ + nc)) * EE + k0);
    s16x8 aef = {0,0,0,0,0,0,0,0};
    if (val) aef = pack8(pe[0], pe[1]);
    if (cw == 0)
      *reinterpret_cast<s16x8*>(ef_bf + ((size_t)(b * NP + nA)) * EE + k0) = aef;
    const f32x4* p1 = reinterpret_cast<const f32x4*>(eq1 + ((size_t)(b * NN_ + nc)) * EE + k0);
    const f32x4* p0 = reinterpret_cast<const f32x4*>(eq0 + ((size_t)(b * NN_ + nc)) * EE + k0);
    s16x8 a1 = pack8(p1[0], p1[1]);
    s16x8 a0 = pack8(p0[0], p0[1]);
#pragma unroll
    for (int tc = 0; tc < 4; ++tc) {
      int e = cw * 64 + tc * 16 + c;
      const unsigned short* wrow = wt + e * EE + k0;
      s16x8 bq1 = *reinterpret_cast<const s16x8*>(wrow);
      s16x8 bq0 = *reinterpret_cast<const s16x8*>(wrow + 1 * 16384);
      s16x8 bk  = *reinterpret_cast<const s16x8*>(wrow + 2 * 16384);
      s16x8 bv  = *reinterpret_cast<const s16x8*>(wrow + 3 * 16384);
      ak[tc] = MFMA(aef, bk, ak[tc]);
      av[tc] = MFMA(aef, bv, av[tc]);
      aq[tc] = MFMA(a1, bq1, aq[tc]);
      aq[tc] = MFMA(a0, bq0, aq[tc]);
    }
  }
#pragma unroll
  for (int tc = 0; tc < 4; ++tc) {
    int h = cw * 4 + tc;                 // e = cw*64+tc*16+c -> head, d = c
#pragma unroll
    for (int r = 0; r < 4; ++r) {
      int n = nbase + 4 * g + r;
      size_t off = ((size_t)((b * NHEAD + h) * NP) + n) * HD + c;
      kh[off] = f2bf(ak[tc][r]);         // padded rows: aef=0 -> ak=0, naturally safe
      qh[off] = f2bf(aq[tc][r]);         // padded rows garbage-but-finite; outputs unused
    }
    int n0 = nbase + 4 * g;
    unsigned pv0 = cvtpk(av[tc][0], av[tc][1]);
    unsigned pv1 = cvtpk(av[tc][2], av[tc][3]);
    *reinterpret_cast<uint2*>(vt_bf + (((size_t)(b * NHEAD + h)) * HD + c) * NP + n0) =
        make_uint2(pv0, pv1);
  }
}

// ---------------- K2: FUSED attn + combine + pointer-logits per (b, 32-row tile) ----------------
// 512 threads = 8 waves. Phase A: wave w owns head h=w completely; BOTH 16-row halves are
// computed in ONE m-loop (K/V loaded once, 4 independent QK chains + 2 PV chains per iter)
// with explicit 1-deep K/V prefetch so loads stay in flight across the compute body.
// Zero Phase-A barriers; PV in registers. No max-subtraction (bounded scores; tail cols get
// mask' = -14427 -> exp2 -> exact 0). LDS 40448 B (smask[32][500] + sao[32][132], reds
// aliased on sao).
__global__ __launch_bounds__(512, 4) void k_fused(
    const unsigned short* __restrict__ qh, const unsigned short* __restrict__ kh,
    const unsigned short* __restrict__ vt, const unsigned short* __restrict__ ef_bf,
    const unsigned short* __restrict__ wt, const float* __restrict__ bcp,
    const float* __restrict__ mask, float* __restrict__ probs) {
  int wgid = blockIdx.x;                 // 1024
  int xcd = wgid & 7;
  int s = wgid >> 3;
  int nt = s & 15;
  int b = (s >> 4) * 8 + xcd;            // all 16 tiles of b on one XCD
  int tid = threadIdx.x;
  int w = tid >> 6, lane = tid & 63, g = lane >> 4, c = lane & 15;
  int nt32 = nt * 32;

  __shared__ __align__(16) char uni[40448];
  unsigned short (*smask)[500] = reinterpret_cast<unsigned short(*)[500]>(uni);          // 32000 B
  unsigned short (*sao)[132]   = reinterpret_cast<unsigned short(*)[132]>(uni + 32000);  // 8448 B
  float (*reds)[2][16]         = reinterpret_cast<float(*)[2][16]>(uni + 32000);         // aliases sao

  const float LOG2E = 1.4426950408889634f;
  const unsigned short BFNI = f2bf(-14427.0f);

  // ---- stage mask' = log2e * mask as bf16, real 500 cols only ----
  for (int idx = tid; idx < 32 * 125; idx += 512) {
    int rl = idx / 125;
    int m4 = idx - rl * 125;
    int nr = nt32 + rl;
    f32x4 v = {0.f, 0.f, 0.f, 0.f};
    if (nr < NN_) v = *reinterpret_cast<const f32x4*>(mask + ((size_t)b * NN_ + nr) * NN_ + m4 * 4);
    unsigned lo = cvtpk(v[0] * LOG2E, v[1] * LOG2E);
    unsigned hi = cvtpk(v[2] * LOG2E, v[3] * LOG2E);
    *reinterpret_cast<uint2*>(&smask[rl][m4 * 4]) = make_uint2(lo, hi);
  }
  __syncthreads();                        // S1: smask visible

  // ================= Phase A: attention, wave w = head w, zero barriers =================
  {
    int h = w;
    const unsigned short* qb = qh + ((size_t)(b * NHEAD + h)) * NP * HD;
    const unsigned short* kb = kh + ((size_t)(b * NHEAD + h)) * NP * HD;
    const unsigned short* vrow = vt + (((size_t)(b * NHEAD + h)) * HD + c) * NP;

    s16x4 q40 = *reinterpret_cast<const s16x4*>(qb + (nt32 + c) * HD + 4 * g);
    s16x4 q41 = *reinterpret_cast<const s16x4*>(qb + (nt32 + 16 + c) * HD + 4 * g);
    s16x8 bq0 = { q40[0], q40[1], q40[2], q40[3], 0, 0, 0, 0 };
    s16x8 bq1 = { q41[0], q41[1], q41[2], q41[3], 0, 0, 0, 0 };

    f32x4 o0 = {0,0,0,0}, o1 = {0,0,0,0};
    float ls0 = 0.0f, ls1 = 0.0f;

    // prefetch mt = 0
    s16x4 k40 = *reinterpret_cast<const s16x4*>(kb + c * HD + 4 * g);
    s16x4 k41 = *reinterpret_cast<const s16x4*>(kb + (16 + c) * HD + 4 * g);
    s16x4 va  = *reinterpret_cast<const s16x4*>(vrow + 4 * g);
    s16x4 v2  = *reinterpret_cast<const s16x4*>(vrow + 16 + 4 * g);

    for (int mt = 0; mt < 16; ++mt) {
      int m0 = mt * 32;
      s16x8 kf0 = { k40[0], k40[1], k40[2], k40[3], 0, 0, 0, 0 };
      s16x8 kf1 = { k41[0], k41[1], k41[2], k41[3], 0, 0, 0, 0 };
      s16x8 af  = { va[0], va[1], va[2], va[3], v2[0], v2[1], v2[2], v2[3] };
      if (mt < 15) {                      // prefetch mt+1 (rows <= 511, padded region is 0)
        k40 = *reinterpret_cast<const s16x4*>(kb + (m0 + 32 + c) * HD + 4 * g);
        k41 = *reinterpret_cast<const s16x4*>(kb + (m0 + 48 + c) * HD + 4 * g);
        va  = *reinterpret_cast<const s16x4*>(vrow + m0 + 32 + 4 * g);
        v2  = *reinterpret_cast<const s16x4*>(vrow + m0 + 48 + 4 * g);
      }
      s16x4 mk00 = *reinterpret_cast<const s16x4*>(&smask[c][m0 + 4 * g]);
      s16x4 mk10 = *reinterpret_cast<const s16x4*>(&smask[16 + c][m0 + 4 * g]);
      s16x4 mk01, mk11;
      if (mt < 15 || g == 0) {
        mk01 = *reinterpret_cast<const s16x4*>(&smask[c][m0 + 16 + 4 * g]);
        mk11 = *reinterpret_cast<const s16x4*>(&smask[16 + c][m0 + 16 + 4 * g]);
      } else {
        mk01 = (s16x4){ (short)BFNI, (short)BFNI, (short)BFNI, (short)BFNI };
        mk11 = mk01;
      }
      f32x4 a0 = MFMA(kf0, bq0, (f32x4){0,0,0,0});
      f32x4 a1 = MFMA(kf1, bq0, (f32x4){0,0,0,0});
      f32x4 b0 = MFMA(kf0, bq1, (f32x4){0,0,0,0});
      f32x4 b1 = MFMA(kf1, bq1, (f32x4){0,0,0,0});
#pragma unroll
      for (int j = 0; j < 4; ++j) {
        a0[j] = EXP2(fmaf(a0[j], 0.36067376022224085f, bf2f((unsigned short)mk00[j])));
        a1[j] = EXP2(fmaf(a1[j], 0.36067376022224085f, bf2f((unsigned short)mk01[j])));
        ls0 += a0[j] + a1[j];
        b0[j] = EXP2(fmaf(b0[j], 0.36067376022224085f, bf2f((unsigned short)mk10[j])));
        b1[j] = EXP2(fmaf(b1[j], 0.36067376022224085f, bf2f((unsigned short)mk11[j])));
        ls1 += b0[j] + b1[j];
      }
      o0 = MFMA(af, pack8_m(a0, a1), o0);  // s_nop-hardened packs feed MFMA SrcB
      o1 = MFMA(af, pack8_m(b0, b1), o1);
    }
    ls0 += __shfl_xor(ls0, 16);
    ls0 += __shfl_xor(ls0, 32);
    ls1 += __shfl_xor(ls1, 16);
    ls1 += __shfl_xor(ls1, 32);
    float inv0 = RCP(ls0), inv1 = RCP(ls1);
    *reinterpret_cast<uint2*>(&sao[c][w * HD + 4 * g]) =
        make_uint2(cvtpk(o0[0] * inv0, o0[1] * inv0), cvtpk(o0[2] * inv0, o0[3] * inv0));
    *reinterpret_cast<uint2*>(&sao[16 + c][w * HD + 4 * g]) =
        make_uint2(cvtpk(o1[0] * inv1, o1[1] * inv1), cvtpk(o1[2] * inv1, o1[3] * inv1));
  }
  __syncthreads();                        // A1: sao (ao tile) complete

  // ================= Phase B: mh = ao @ Wc + bc =================
  int mw = w & 3, nw = w >> 2;
  float bias0 = bcp[mw * 32 + c];
  float bias1 = bcp[mw * 32 + 16 + c];
  f32x4 acm0 = {0,0,0,0}, acm1 = {0,0,0,0};
#pragma unroll
  for (int kk = 0; kk < 4; ++kk) {
    int k0 = kk * 32 + 8 * g;
    s16x8 aa = *reinterpret_cast<const s16x8*>(&sao[nw * 16 + c][k0]);
    s16x8 bw0 = *reinterpret_cast<const s16x8*>(wt + 4 * 16384 + (mw * 32 + c) * EE + k0);
    s16x8 bw1 = *reinterpret_cast<const s16x8*>(wt + 4 * 16384 + (mw * 32 + 16 + c) * EE + k0);
    acm0 = MFMA(aa, bw0, acm0);
    acm1 = MFMA(aa, bw1, acm1);
  }
  __syncthreads();                        // B1: all sao reads done
#pragma unroll
  for (int r = 0; r < 4; ++r) {
    sao[nw * 16 + 4 * g + r][mw * 32 + c]      = f2bf(acm0[r] + bias0);
    sao[nw * 16 + 4 * g + r][mw * 32 + 16 + c] = f2bf(acm1[r] + bias1);
  }
  __syncthreads();                        // B2: mh tile ready

  // ================= Phase C: pointer logits + softmax (no max-sub; tanh bounds) =====
  f32x4 sc[8];
#pragma unroll
  for (int t = 0; t < 8; ++t) sc[t] = (f32x4){0,0,0,0};
#pragma unroll
  for (int kk = 0; kk < 4; ++kk) {
    int k0 = kk * 32 + 8 * g;
    s16x8 am = *reinterpret_cast<const s16x8*>(&sao[nw * 16 + c][k0]);
#pragma unroll
    for (int t = 0; t < 8; ++t) {
      int m = mw * 128 + t * 16 + c;
      s16x8 bfr = *reinterpret_cast<const s16x8*>(ef_bf + ((size_t)(b * NP + m)) * EE + k0);
      sc[t] = MFMA(am, bfr, sc[t]);
    }
  }
  float rsum[4] = {0, 0, 0, 0};
#pragma unroll
  for (int t = 0; t < 8; ++t) {
    int m = mw * 128 + t * 16 + c;
    bool mok = (m < NN_);
#pragma unroll
    for (int r = 0; r < 4; ++r) {
      float x = sc[t][r] * 0.08838834764831845f;   // 1/sqrt(128)
      float ax = fabsf(x);
      float e2 = EXP2(ax * 2.8853900817779268f);   // e^(2|x|)
      float th = copysignf(1.0f - 2.0f * RCP(e2 + 1.0f), x);
      float mm = mok ? bf2f(smask[nw * 16 + 4 * g + r][m]) : -14427.0f;
      float p = EXP2(fmaf(th, 14.426950408889634f, mm));
      sc[t][r] = p;                                 // m>=500 -> p = 0
      rsum[r] += p;
    }
  }
#pragma unroll
  for (int r = 0; r < 4; ++r) {
    rsum[r] += __shfl_xor(rsum[r], 1);
    rsum[r] += __shfl_xor(rsum[r], 2);
    rsum[r] += __shfl_xor(rsum[r], 4);
    rsum[r] += __shfl_xor(rsum[r], 8);
  }
  __syncthreads();                        // C0: sao fully dead; reds may overwrite it
  if (c == 0) {
#pragma unroll
    for (int r = 0; r < 4; ++r) reds[mw][nw][4 * g + r] = rsum[r];
  }
  __syncthreads();                        // C1
  float inv[4];
#pragma unroll
  for (int r = 0; r < 4; ++r) {
    int rr = 4 * g + r;
    inv[r] = RCP(reds[0][nw][rr] + reds[1][nw][rr] + reds[2][nw][rr] + reds[3][nw][rr]);
  }
#pragma unroll
  for (int t = 0; t < 8; ++t) {
    int m = mw * 128 + t * 16 + c;
    if (m < NN_) {
#pragma unroll
      for (int r = 0; r < 4; ++r) {
        int ng = nt32 + nw * 16 + 4 * g + r;
        if (ng < NN_) probs[((size_t)b * NN_ + ng) * NN_ + m] = sc[t][r] * inv[r];
      }
    }
  }
}

extern "C" void kernel_launch(void* const* d_in, const int* in_sizes, int n_in,
                              void* d_out, int out_size, void* d_ws, size_t ws_size,
                              hipStream_t stream) {
  const float* ef   = (const float*)d_in[0];
  const float* eq1  = (const float*)d_in[1];
  const float* eq0  = (const float*)d_in[2];
  const float* mask = (const float*)d_in[3];
  const float* wq1  = (const float*)d_in[4];
  const float* wq0  = (const float*)d_in[5];
  const float* wk   = (const float*)d_in[6];
  const float* wv   = (const float*)d_in[7];
  const float* wc   = (const float*)d_in[8];
  const float* bc   = (const float*)d_in[9];
  float* probs = (float*)d_out;

  char* ws = (char*)d_ws;
  const size_t SL = 8388608;  // 64*512*128*2 bytes
  unsigned short* ef_bf = (unsigned short*)(ws);
  unsigned short* qh    = (unsigned short*)(ws + 1 * SL);
  unsigned short* kh    = (unsigned short*)(ws + 2 * SL);
  unsigned short* vt_bf = (unsigned short*)(ws + 3 * SL);
  unsigned short* wt    = (unsigned short*)(ws + 4 * SL);

  k_conv_w<<<320, 256, 0, stream>>>(wq1, wq0, wk, wv, wc, wt);
  k_proj<<<1024, 256, 0, stream>>>(ef, eq1, eq0, wt, qh, kh, vt_bf, ef_bf);
  k_fused<<<1024, 512, 0, stream>>>(qh, kh, vt_bf, ef_bf, wt, bc, mask, probs);
}

// Round 10
// 123.846 us; speedup vs baseline: 1.4888x; 1.2186x over previous
//
#include <hip/hip_runtime.h>
#include <hip/hip_bf16.h>
#include <cstdint>

#define BB 64
#define NN_ 500
#define NP 512
#define EE 128
#define NHEAD 8
#define HD 16

typedef float f32x4 __attribute__((ext_vector_type(4)));
typedef unsigned u32x4 __attribute__((ext_vector_type(4)));
typedef short s16x8 __attribute__((ext_vector_type(8)));
typedef short s16x4 __attribute__((ext_vector_type(4)));

__device__ __forceinline__ unsigned short f2bf(float f) {
  unsigned u = __builtin_bit_cast(unsigned, f);
  u += 0x7FFFu + ((u >> 16) & 1u);
  return (unsigned short)(u >> 16);
}

__device__ __forceinline__ float bf2f(unsigned short u) {
  unsigned v = ((unsigned)u) << 16;
  return __builtin_bit_cast(float, v);
}

__device__ __forceinline__ unsigned cvtpk(float a, float b) {
  unsigned r;
  asm("v_cvt_pk_bf16_f32 %0, %1, %2" : "=v"(r) : "v"(a), "v"(b));
  return r;
}

// cvtpk whose result feeds an MFMA operand: pad 2 wait-states inside the asm so the
// VALU-write -> MFMA-read distance is guaranteed independent of scheduling.
__device__ __forceinline__ unsigned cvtpk_m(float a, float b) {
  unsigned r;
  asm("v_cvt_pk_bf16_f32 %0, %1, %2\n\ts_nop 1" : "=v"(r) : "v"(a), "v"(b));
  return r;
}

__device__ __forceinline__ float EXP2(float x) {
  float r;
  asm("v_exp_f32 %0, %1" : "=v"(r) : "v"(x));
  return r;
}

__device__ __forceinline__ float RCP(float x) {
  float r;
  asm("v_rcp_f32 %0, %1" : "=v"(r) : "v"(x));
  return r;
}

__device__ __forceinline__ s16x8 pack8(f32x4 a, f32x4 b) {
  u32x4 u = { cvtpk(a[0], a[1]), cvtpk(a[2], a[3]), cvtpk(b[0], b[1]), cvtpk(b[2], b[3]) };
  return __builtin_bit_cast(s16x8, u);
}

__device__ __forceinline__ s16x8 pack8_m(f32x4 a, f32x4 b) {
  u32x4 u = { cvtpk_m(a[0], a[1]), cvtpk_m(a[2], a[3]), cvtpk_m(b[0], b[1]), cvtpk_m(b[2], b[3]) };
  return __builtin_bit_cast(s16x8, u);
}

__device__ __forceinline__ f32x4 MFMA(s16x8 a, s16x8 b, f32x4 c) {
  return __builtin_amdgcn_mfma_f32_16x16x32_bf16(a, b, c, 0, 0, 0);
}

// ---------------- K0b: W^T bf16; mats order [q1,q0,k,v,c], WT[m][n][k]=W[k][n] ----------------
__global__ void k_conv_w(const float* __restrict__ w0, const float* __restrict__ w1,
                         const float* __restrict__ w2, const float* __restrict__ w3,
                         const float* __restrict__ w4, unsigned short* __restrict__ wt) {
  int idx = blockIdx.x * 256 + threadIdx.x;   // 5*128*128 = 81920
  int k = idx & 127;
  int n = (idx >> 7) & 127;
  int m = idx >> 14;
  const float* w = (m == 0) ? w0 : (m == 1) ? w1 : (m == 2) ? w2 : (m == 3) ? w3 : w4;
  wt[idx] = f2bf(w[k * 128 + n]);
}

// ---------------- K1: projections -> qh row-layout; khf/vtf/eff in MFMA-fragment lane order ----
// khf[b][h][mt][lane]: {K[m0+c][4g..4g+3], K[m0+16+c][4g..4g+3]}   (16B/lane, coalesced)
// vtf[b][h][mt][lane]: {V[m0+4g..+3][c],   V[m0+16+4g..+3][c]}      (= PV A-fragment af)
// eff[b][rt][kk][lane]: ef[rt*16+c][kk*32+8g..+7]                    (= Phase-C B-fragment)
// K/V go through a small LDS transpose; eff is a direct register store (aef IS the fragment).
__global__ __launch_bounds__(256) void k_proj(
    const float* __restrict__ ef,
    const float* __restrict__ eq1, const float* __restrict__ eq0,
    const unsigned short* __restrict__ wt,
    unsigned short* __restrict__ qh, unsigned short* __restrict__ khf,
    unsigned short* __restrict__ vtf, unsigned short* __restrict__ eff) {
  int wgid = blockIdx.x;                 // 1024
  int xcd = wgid & 7;
  int s = wgid >> 3;
  int nt = s & 15;
  int b = (s >> 4) * 8 + xcd;
  int tid = threadIdx.x;
  int w = tid >> 6, lane = tid & 63, g = lane >> 4, c = lane & 15;
  int rw = w & 1, cw = w >> 1;
  int nbase = nt * 32 + rw * 16;

  __shared__ unsigned short sk[8][32][20];   // 10240 B  [h][n_loc][d], stride 20 -> 8B-aligned reads
  __shared__ unsigned short sv[8][16][36];   // 9216 B   [h][d][n_loc], stride 36 -> 8B-aligned reads

  f32x4 ak[4], av[4], aq[4];
#pragma unroll
  for (int t = 0; t < 4; ++t) { ak[t]=(f32x4){0,0,0,0}; av[t]=(f32x4){0,0,0,0}; aq[t]=(f32x4){0,0,0,0}; }

  int nA = nbase + c;
  int nc = nA < NN_ ? nA : NN_ - 1;
  bool val = (nA < NN_);

  for (int kk = 0; kk < 4; ++kk) {
    int k0 = kk * 32 + 8 * g;
    const f32x4* pe = reinterpret_cast<const f32x4*>(ef + ((size_t)(b * NN_ + nc)) * EE + k0);
    s16x8 aef = {0,0,0,0,0,0,0,0};
    if (val) aef = pack8(pe[0], pe[1]);
    if (cw == 0)                          // eff: direct fragment store, coalesced 16B/lane
      *reinterpret_cast<s16x8*>(eff + (((size_t)(b * 32 + 2 * nt + rw)) * 4 + kk) * 512 + lane * 8) = aef;
    const f32x4* p1 = reinterpret_cast<const f32x4*>(eq1 + ((size_t)(b * NN_ + nc)) * EE + k0);
    const f32x4* p0 = reinterpret_cast<const f32x4*>(eq0 + ((size_t)(b * NN_ + nc)) * EE + k0);
    s16x8 a1 = pack8(p1[0], p1[1]);
    s16x8 a0 = pack8(p0[0], p0[1]);
#pragma unroll
    for (int tc = 0; tc < 4; ++tc) {
      int e = cw * 64 + tc * 16 + c;
      const unsigned short* wrow = wt + e * EE + k0;
      s16x8 bq1 = *reinterpret_cast<const s16x8*>(wrow);
      s16x8 bq0 = *reinterpret_cast<const s16x8*>(wrow + 1 * 16384);
      s16x8 bk  = *reinterpret_cast<const s16x8*>(wrow + 2 * 16384);
      s16x8 bv  = *reinterpret_cast<const s16x8*>(wrow + 3 * 16384);
      ak[tc] = MFMA(aef, bk, ak[tc]);
      av[tc] = MFMA(aef, bv, av[tc]);
      aq[tc] = MFMA(a1, bq1, aq[tc]);
      aq[tc] = MFMA(a0, bq0, aq[tc]);
    }
  }
#pragma unroll
  for (int tc = 0; tc < 4; ++tc) {
    int h = cw * 4 + tc;                 // e = cw*64+tc*16+c -> head, d = c
#pragma unroll
    for (int r = 0; r < 4; ++r) {
      int nloc = rw * 16 + 4 * g + r;
      int n = nt * 32 + nloc;
      qh[((size_t)((b * NHEAD + h) * NP) + n) * HD + c] = f2bf(aq[tc][r]);
      sk[h][nloc][c] = f2bf(ak[tc][r]);  // pad rows: aef=0 -> ak=0
      sv[h][c][nloc] = f2bf(av[tc][r]);
    }
  }
  __syncthreads();
  // re-read in fragment order, write coalesced 16B/lane; wave w covers heads 2w, 2w+1
#pragma unroll
  for (int i = 0; i < 2; ++i) {
    int h = 2 * w + i;
    size_t base = (((size_t)(b * NHEAD + h)) * 16 + nt) * 512 + lane * 8;
    s16x4 klo = *reinterpret_cast<const s16x4*>(&sk[h][c][4 * g]);
    s16x4 khi = *reinterpret_cast<const s16x4*>(&sk[h][16 + c][4 * g]);
    s16x8 kfr = { klo[0], klo[1], klo[2], klo[3], khi[0], khi[1], khi[2], khi[3] };
    *reinterpret_cast<s16x8*>(khf + base) = kfr;
    s16x4 vlo = *reinterpret_cast<const s16x4*>(&sv[h][c][4 * g]);
    s16x4 vhi = *reinterpret_cast<const s16x4*>(&sv[h][c][16 + 4 * g]);
    s16x8 vfr = { vlo[0], vlo[1], vlo[2], vlo[3], vhi[0], vhi[1], vhi[2], vhi[3] };
    *reinterpret_cast<s16x8*>(vtf + base) = vfr;
  }
}

// ---------------- K2: FUSED attn + combine + pointer-logits per (b, 32-row tile) ----------------
// 512 threads = 8 waves. Phase A: wave w = head w, both 16-row halves in one m-loop, PV in
// registers, zero Phase-A barriers; K/V are single 16B fully-coalesced fragment loads with
// 2-deep prefetch. Phase C: ef fragments (eff) also single coalesced 16B loads.
// No max-subtraction (bounded scores; tail handled by mask' = -14427 -> exp2 -> exact 0).
// LDS 40448 B (smask[32][500] + sao[32][132], reds aliased on sao).
__global__ __launch_bounds__(512, 4) void k_fused(
    const unsigned short* __restrict__ qh, const unsigned short* __restrict__ khf,
    const unsigned short* __restrict__ vtf, const unsigned short* __restrict__ eff,
    const unsigned short* __restrict__ wt, const float* __restrict__ bcp,
    const float* __restrict__ mask, float* __restrict__ probs) {
  int wgid = blockIdx.x;                 // 1024
  int xcd = wgid & 7;
  int s = wgid >> 3;
  int nt = s & 15;
  int b = (s >> 4) * 8 + xcd;            // all 16 tiles of b on one XCD
  int tid = threadIdx.x;
  int w = tid >> 6, lane = tid & 63, g = lane >> 4, c = lane & 15;
  int nt32 = nt * 32;

  __shared__ __align__(16) char uni[40448];
  unsigned short (*smask)[500] = reinterpret_cast<unsigned short(*)[500]>(uni);          // 32000 B
  unsigned short (*sao)[132]   = reinterpret_cast<unsigned short(*)[132]>(uni + 32000);  // 8448 B
  float (*reds)[2][16]         = reinterpret_cast<float(*)[2][16]>(uni + 32000);         // aliases sao

  const float LOG2E = 1.4426950408889634f;
  const unsigned short BFNI = f2bf(-14427.0f);

  // ---- stage mask' = log2e * mask as bf16, real 500 cols only ----
  for (int idx = tid; idx < 32 * 125; idx += 512) {
    int rl = idx / 125;
    int m4 = idx - rl * 125;
    int nr = nt32 + rl;
    f32x4 v = {0.f, 0.f, 0.f, 0.f};
    if (nr < NN_) v = *reinterpret_cast<const f32x4*>(mask + ((size_t)b * NN_ + nr) * NN_ + m4 * 4);
    unsigned lo = cvtpk(v[0] * LOG2E, v[1] * LOG2E);
    unsigned hi = cvtpk(v[2] * LOG2E, v[3] * LOG2E);
    *reinterpret_cast<uint2*>(&smask[rl][m4 * 4]) = make_uint2(lo, hi);
  }
  __syncthreads();                        // S1: smask visible

  // ================= Phase A: attention, wave w = head w, zero barriers =================
  {
    int h = w;
    const unsigned short* qb = qh + ((size_t)(b * NHEAD + h)) * NP * HD;
    const unsigned short* kf_base = khf + (((size_t)(b * NHEAD + h)) * 16) * 512 + lane * 8;
    const unsigned short* vf_base = vtf + (((size_t)(b * NHEAD + h)) * 16) * 512 + lane * 8;

    s16x4 q40 = *reinterpret_cast<const s16x4*>(qb + (nt32 + c) * HD + 4 * g);
    s16x4 q41 = *reinterpret_cast<const s16x4*>(qb + (nt32 + 16 + c) * HD + 4 * g);
    s16x8 bq0 = { q40[0], q40[1], q40[2], q40[3], 0, 0, 0, 0 };
    s16x8 bq1 = { q41[0], q41[1], q41[2], q41[3], 0, 0, 0, 0 };

    f32x4 o0 = {0,0,0,0}, o1 = {0,0,0,0};
    float ls0 = 0.0f, ls1 = 0.0f;

    // 2-deep prefetch of the coalesced K/V fragment loads
    s16x8 kvA = *reinterpret_cast<const s16x8*>(kf_base);
    s16x8 vvA = *reinterpret_cast<const s16x8*>(vf_base);
    s16x8 kvB = *reinterpret_cast<const s16x8*>(kf_base + 512);
    s16x8 vvB = *reinterpret_cast<const s16x8*>(vf_base + 512);

    for (int mt = 0; mt < 16; ++mt) {
      int m0 = mt * 32;
      s16x8 kv = kvA, af = vvA;
      kvA = kvB; vvA = vvB;
      if (mt < 14) {
        kvB = *reinterpret_cast<const s16x8*>(kf_base + (mt + 2) * 512);
        vvB = *reinterpret_cast<const s16x8*>(vf_base + (mt + 2) * 512);
      }
      s16x8 kf0 = { kv[0], kv[1], kv[2], kv[3], 0, 0, 0, 0 };
      s16x8 kf1 = { kv[4], kv[5], kv[6], kv[7], 0, 0, 0, 0 };
      s16x4 mk00 = *reinterpret_cast<const s16x4*>(&smask[c][m0 + 4 * g]);
      s16x4 mk10 = *reinterpret_cast<const s16x4*>(&smask[16 + c][m0 + 4 * g]);
      s16x4 mk01, mk11;
      if (mt < 15 || g == 0) {
        mk01 = *reinterpret_cast<const s16x4*>(&smask[c][m0 + 16 + 4 * g]);
        mk11 = *reinterpret_cast<const s16x4*>(&smask[16 + c][m0 + 16 + 4 * g]);
      } else {
        mk01 = (s16x4){ (short)BFNI, (short)BFNI, (short)BFNI, (short)BFNI };
        mk11 = mk01;
      }
      f32x4 a0 = MFMA(kf0, bq0, (f32x4){0,0,0,0});
      f32x4 a1 = MFMA(kf1, bq0, (f32x4){0,0,0,0});
      f32x4 b0 = MFMA(kf0, bq1, (f32x4){0,0,0,0});
      f32x4 b1 = MFMA(kf1, bq1, (f32x4){0,0,0,0});
#pragma unroll
      for (int j = 0; j < 4; ++j) {
        a0[j] = EXP2(fmaf(a0[j], 0.36067376022224085f, bf2f((unsigned short)mk00[j])));
        a1[j] = EXP2(fmaf(a1[j], 0.36067376022224085f, bf2f((unsigned short)mk01[j])));
        ls0 += a0[j] + a1[j];
        b0[j] = EXP2(fmaf(b0[j], 0.36067376022224085f, bf2f((unsigned short)mk10[j])));
        b1[j] = EXP2(fmaf(b1[j], 0.36067376022224085f, bf2f((unsigned short)mk11[j])));
        ls1 += b0[j] + b1[j];
      }
      o0 = MFMA(af, pack8_m(a0, a1), o0);  // s_nop-hardened packs feed MFMA SrcB
      o1 = MFMA(af, pack8_m(b0, b1), o1);
    }
    ls0 += __shfl_xor(ls0, 16);
    ls0 += __shfl_xor(ls0, 32);
    ls1 += __shfl_xor(ls1, 16);
    ls1 += __shfl_xor(ls1, 32);
    float inv0 = RCP(ls0), inv1 = RCP(ls1);
    *reinterpret_cast<uint2*>(&sao[c][w * HD + 4 * g]) =
        make_uint2(cvtpk(o0[0] * inv0, o0[1] * inv0), cvtpk(o0[2] * inv0, o0[3] * inv0));
    *reinterpret_cast<uint2*>(&sao[16 + c][w * HD + 4 * g]) =
        make_uint2(cvtpk(o1[0] * inv1, o1[1] * inv1), cvtpk(o1[2] * inv1, o1[3] * inv1));
  }
  __syncthreads();                        // A1: sao (ao tile) complete

  // ================= Phase B: mh = ao @ Wc + bc =================
  int mw = w & 3, nw = w >> 2;
  float bias0 = bcp[mw * 32 + c];
  float bias1 = bcp[mw * 32 + 16 + c];
  f32x4 acm0 = {0,0,0,0}, acm1 = {0,0,0,0};
#pragma unroll
  for (int kk = 0; kk < 4; ++kk) {
    int k0 = kk * 32 + 8 * g;
    s16x8 aa = *reinterpret_cast<const s16x8*>(&sao[nw * 16 + c][k0]);
    s16x8 bw0 = *reinterpret_cast<const s16x8*>(wt + 4 * 16384 + (mw * 32 + c) * EE + k0);
    s16x8 bw1 = *reinterpret_cast<const s16x8*>(wt + 4 * 16384 + (mw * 32 + 16 + c) * EE + k0);
    acm0 = MFMA(aa, bw0, acm0);
    acm1 = MFMA(aa, bw1, acm1);
  }
  __syncthreads();                        // B1: all sao reads done
#pragma unroll
  for (int r = 0; r < 4; ++r) {
    sao[nw * 16 + 4 * g + r][mw * 32 + c]      = f2bf(acm0[r] + bias0);
    sao[nw * 16 + 4 * g + r][mw * 32 + 16 + c] = f2bf(acm1[r] + bias1);
  }
  __syncthreads();                        // B2: mh tile ready

  // ================= Phase C: pointer logits + softmax (no max-sub; tanh bounds) =====
  f32x4 sc[8];
#pragma unroll
  for (int t = 0; t < 8; ++t) sc[t] = (f32x4){0,0,0,0};
#pragma unroll
  for (int kk = 0; kk < 4; ++kk) {
    int k0 = kk * 32 + 8 * g;
    s16x8 am = *reinterpret_cast<const s16x8*>(&sao[nw * 16 + c][k0]);
#pragma unroll
    for (int t = 0; t < 8; ++t) {
      s16x8 bfr = *reinterpret_cast<const s16x8*>(
          eff + (((size_t)(b * 32 + mw * 8 + t)) * 4 + kk) * 512 + lane * 8);
      sc[t] = MFMA(am, bfr, sc[t]);
    }
  }
  float rsum[4] = {0, 0, 0, 0};
#pragma unroll
  for (int t = 0; t < 8; ++t) {
    int m = mw * 128 + t * 16 + c;
    bool mok = (m < NN_);
#pragma unroll
    for (int r = 0; r < 4; ++r) {
      float x = sc[t][r] * 0.08838834764831845f;   // 1/sqrt(128)
      float ax = fabsf(x);
      float e2 = EXP2(ax * 2.8853900817779268f);   // e^(2|x|)
      float th = copysignf(1.0f - 2.0f * RCP(e2 + 1.0f), x);
      float mm = mok ? bf2f(smask[nw * 16 + 4 * g + r][m]) : -14427.0f;
      float p = EXP2(fmaf(th, 14.426950408889634f, mm));
      sc[t][r] = p;                                 // m>=500 -> p = 0
      rsum[r] += p;
    }
  }
#pragma unroll
  for (int r = 0; r < 4; ++r) {
    rsum[r] += __shfl_xor(rsum[r], 1);
    rsum[r] += __shfl_xor(rsum[r], 2);
    rsum[r] += __shfl_xor(rsum[r], 4);
    rsum[r] += __shfl_xor(rsum[r], 8);
  }
  __syncthreads();                        // C0: sao fully dead; reds may overwrite it
  if (c == 0) {
#pragma unroll
    for (int r = 0; r < 4; ++r) reds[mw][nw][4 * g + r] = rsum[r];
  }
  __syncthreads();                        // C1
  float inv[4];
#pragma unroll
  for (int r = 0; r < 4; ++r) {
    int rr = 4 * g + r;
    inv[r] = RCP(reds[0][nw][rr] + reds[1][nw][rr] + reds[2][nw][rr] + reds[3][nw][rr]);
  }
#pragma unroll
  for (int t = 0; t < 8; ++t) {
    int m = mw * 128 + t * 16 + c;
    if (m < NN_) {
#pragma unroll
      for (int r = 0; r < 4; ++r) {
        int ng = nt32 + nw * 16 + 4 * g + r;
        if (ng < NN_) probs[((size_t)b * NN_ + ng) * NN_ + m] = sc[t][r] * inv[r];
      }
    }
  }
}

extern "C" void kernel_launch(void* const* d_in, const int* in_sizes, int n_in,
                              void* d_out, int out_size, void* d_ws, size_t ws_size,
                              hipStream_t stream) {
  const float* ef   = (const float*)d_in[0];
  const float* eq1  = (const float*)d_in[1];
  const float* eq0  = (const float*)d_in[2];
  const float* mask = (const float*)d_in[3];
  const float* wq1  = (const float*)d_in[4];
  const float* wq0  = (const float*)d_in[5];
  const float* wk   = (const float*)d_in[6];
  const float* wv   = (const float*)d_in[7];
  const float* wc   = (const float*)d_in[8];
  const float* bc   = (const float*)d_in[9];
  float* probs = (float*)d_out;

  char* ws = (char*)d_ws;
  const size_t SL = 8388608;  // 64*512*128*2 bytes = 8 MB slots
  unsigned short* qh  = (unsigned short*)(ws);
  unsigned short* khf = (unsigned short*)(ws + 1 * SL);
  unsigned short* vtf = (unsigned short*)(ws + 2 * SL);
  unsigned short* eff = (unsigned short*)(ws + 3 * SL);
  unsigned short* wt  = (unsigned short*)(ws + 4 * SL);

  k_conv_w<<<320, 256, 0, stream>>>(wq1, wq0, wk, wv, wc, wt);
  k_proj<<<1024, 256, 0, stream>>>(ef, eq1, eq0, wt, qh, khf, vtf, eff);
  k_fused<<<1024, 512, 0, stream>>>(qh, khf, vtf, eff, wt, bc, mask, probs);
}

// Round 11
// 116.699 us; speedup vs baseline: 1.5800x; 1.0612x over previous
//
#include <hip/hip_runtime.h>
#include <hip/hip_bf16.h>
#include <cstdint>

#define BB 64
#define NN_ 500
#define NP 512
#define EE 128
#define NHEAD 8
#define HD 16

typedef float f32x4 __attribute__((ext_vector_type(4)));
typedef unsigned u32x4 __attribute__((ext_vector_type(4)));
typedef short s16x8 __attribute__((ext_vector_type(8)));
typedef short s16x4 __attribute__((ext_vector_type(4)));

__device__ __forceinline__ unsigned short f2bf(float f) {
  unsigned u = __builtin_bit_cast(unsigned, f);
  u += 0x7FFFu + ((u >> 16) & 1u);
  return (unsigned short)(u >> 16);
}

__device__ __forceinline__ float bf2f(unsigned short u) {
  unsigned v = ((unsigned)u) << 16;
  return __builtin_bit_cast(float, v);
}

__device__ __forceinline__ float blo(unsigned u) {            // low bf16 of a u32 -> f32
  return __builtin_bit_cast(float, u << 16);
}
__device__ __forceinline__ float bhi(unsigned u) {            // high bf16 of a u32 -> f32
  return __builtin_bit_cast(float, u & 0xFFFF0000u);
}

__device__ __forceinline__ unsigned cvtpk(float a, float b) {
  unsigned r;
  asm("v_cvt_pk_bf16_f32 %0, %1, %2" : "=v"(r) : "v"(a), "v"(b));
  return r;
}

// cvtpk whose result feeds an MFMA operand: pad 2 wait-states inside the asm so the
// VALU-write -> MFMA-read distance is guaranteed independent of scheduling.
__device__ __forceinline__ unsigned cvtpk_m(float a, float b) {
  unsigned r;
  asm("v_cvt_pk_bf16_f32 %0, %1, %2\n\ts_nop 1" : "=v"(r) : "v"(a), "v"(b));
  return r;
}

__device__ __forceinline__ float EXP2(float x) {
  float r;
  asm("v_exp_f32 %0, %1" : "=v"(r) : "v"(x));
  return r;
}

__device__ __forceinline__ float RCP(float x) {
  float r;
  asm("v_rcp_f32 %0, %1" : "=v"(r) : "v"(x));
  return r;
}

__device__ __forceinline__ s16x8 pack8(f32x4 a, f32x4 b) {
  u32x4 u = { cvtpk(a[0], a[1]), cvtpk(a[2], a[3]), cvtpk(b[0], b[1]), cvtpk(b[2], b[3]) };
  return __builtin_bit_cast(s16x8, u);
}

__device__ __forceinline__ s16x8 pack8_m(f32x4 a, f32x4 b) {
  u32x4 u = { cvtpk_m(a[0], a[1]), cvtpk_m(a[2], a[3]), cvtpk_m(b[0], b[1]), cvtpk_m(b[2], b[3]) };
  return __builtin_bit_cast(s16x8, u);
}

__device__ __forceinline__ f32x4 MFMA(s16x8 a, s16x8 b, f32x4 c) {
  return __builtin_amdgcn_mfma_f32_16x16x32_bf16(a, b, c, 0, 0, 0);
}

// ---------------- K0b: W^T bf16; coalesced float4 reads, scattered 2B writes ----------------
__global__ void k_conv_w(const float* __restrict__ w0, const float* __restrict__ w1,
                         const float* __restrict__ w2, const float* __restrict__ w3,
                         const float* __restrict__ w4, unsigned short* __restrict__ wt) {
  int t = blockIdx.x * 256 + threadIdx.x;     // 5*128*32 = 20480
  int n4 = t & 31;
  int k  = (t >> 5) & 127;
  int m  = t >> 12;
  const float* w = (m == 0) ? w0 : (m == 1) ? w1 : (m == 2) ? w2 : (m == 3) ? w3 : w4;
  float4 v = *reinterpret_cast<const float4*>(w + k * 128 + n4 * 4);
  unsigned short* o = wt + m * 16384 + k;     // wt[m][n][k] = w[k][n]
  o[(n4 * 4 + 0) * 128] = f2bf(v.x);
  o[(n4 * 4 + 1) * 128] = f2bf(v.y);
  o[(n4 * 4 + 2) * 128] = f2bf(v.z);
  o[(n4 * 4 + 3) * 128] = f2bf(v.w);
}

// ---------------- K1: projections -> qhf/khf/vtf/eff ALL in MFMA-fragment lane order ----------
// qhf/khf[b][h][nt/mt][lane]: {X[t0+c][4g..4g+3], X[t0+16+c][4g..4g+3]}  (16B/lane coalesced)
// vtf[b][h][mt][lane]:        {V[m0+4g..+3][c],   V[m0+16+4g..+3][c]}    (= PV A-fragment)
// eff[b][rt][kk][lane]:       ef[rt*16+c][kk*32+8g..+7]                  (= Phase-C B-fragment)
// Q/K/V go through a small LDS transpose; eff is a direct register store. 1-deep prefetch on
// the six input float4 loads across the kk loop.
__global__ __launch_bounds__(256) void k_proj(
    const float* __restrict__ ef,
    const float* __restrict__ eq1, const float* __restrict__ eq0,
    const unsigned short* __restrict__ wt,
    unsigned short* __restrict__ qhf, unsigned short* __restrict__ khf,
    unsigned short* __restrict__ vtf, unsigned short* __restrict__ eff) {
  int wgid = blockIdx.x;                 // 1024
  int xcd = wgid & 7;
  int s = wgid >> 3;
  int nt = s & 15;
  int b = (s >> 4) * 8 + xcd;
  int tid = threadIdx.x;
  int w = tid >> 6, lane = tid & 63, g = lane >> 4, c = lane & 15;
  int rw = w & 1, cw = w >> 1;
  int nbase = nt * 32 + rw * 16;

  __shared__ unsigned short sk[8][32][20];   // 10240 B
  __shared__ unsigned short sv[8][16][36];   // 9216 B
  __shared__ unsigned short sq[8][32][20];   // 10240 B -> 29696 B total

  f32x4 ak[4], av[4], aq[4];
#pragma unroll
  for (int t = 0; t < 4; ++t) { ak[t]=(f32x4){0,0,0,0}; av[t]=(f32x4){0,0,0,0}; aq[t]=(f32x4){0,0,0,0}; }

  int nA = nbase + c;
  int nc = nA < NN_ ? nA : NN_ - 1;
  bool val = (nA < NN_);

  const float* pe_base = ef  + ((size_t)(b * NN_ + nc)) * EE;
  const float* p1_base = eq1 + ((size_t)(b * NN_ + nc)) * EE;
  const float* p0_base = eq0 + ((size_t)(b * NN_ + nc)) * EE;

  // prefetch kk = 0
  int k0p = 8 * g;
  f32x4 eA  = *reinterpret_cast<const f32x4*>(pe_base + k0p);
  f32x4 eB  = *reinterpret_cast<const f32x4*>(pe_base + k0p + 4);
  f32x4 u1A = *reinterpret_cast<const f32x4*>(p1_base + k0p);
  f32x4 u1B = *reinterpret_cast<const f32x4*>(p1_base + k0p + 4);
  f32x4 u0A = *reinterpret_cast<const f32x4*>(p0_base + k0p);
  f32x4 u0B = *reinterpret_cast<const f32x4*>(p0_base + k0p + 4);

  for (int kk = 0; kk < 4; ++kk) {
    int k0 = kk * 32 + 8 * g;
    s16x8 aef = {0,0,0,0,0,0,0,0};
    if (val) aef = pack8(eA, eB);
    s16x8 a1 = pack8(u1A, u1B);
    s16x8 a0 = pack8(u0A, u0B);
    if (kk < 3) {                         // prefetch kk+1
      int kn = (kk + 1) * 32 + 8 * g;
      eA  = *reinterpret_cast<const f32x4*>(pe_base + kn);
      eB  = *reinterpret_cast<const f32x4*>(pe_base + kn + 4);
      u1A = *reinterpret_cast<const f32x4*>(p1_base + kn);
      u1B = *reinterpret_cast<const f32x4*>(p1_base + kn + 4);
      u0A = *reinterpret_cast<const f32x4*>(p0_base + kn);
      u0B = *reinterpret_cast<const f32x4*>(p0_base + kn + 4);
    }
    if (cw == 0)                          // eff: direct fragment store, coalesced 16B/lane
      *reinterpret_cast<s16x8*>(eff + (((size_t)(b * 32 + 2 * nt + rw)) * 4 + kk) * 512 + lane * 8) = aef;
#pragma unroll
    for (int tc = 0; tc < 4; ++tc) {
      int e = cw * 64 + tc * 16 + c;
      const unsigned short* wrow = wt + e * EE + k0;
      s16x8 bq1 = *reinterpret_cast<const s16x8*>(wrow);
      s16x8 bq0 = *reinterpret_cast<const s16x8*>(wrow + 1 * 16384);
      s16x8 bk  = *reinterpret_cast<const s16x8*>(wrow + 2 * 16384);
      s16x8 bv  = *reinterpret_cast<const s16x8*>(wrow + 3 * 16384);
      ak[tc] = MFMA(aef, bk, ak[tc]);
      av[tc] = MFMA(aef, bv, av[tc]);
      aq[tc] = MFMA(a1, bq1, aq[tc]);
      aq[tc] = MFMA(a0, bq0, aq[tc]);
    }
  }
#pragma unroll
  for (int tc = 0; tc < 4; ++tc) {
    int h = cw * 4 + tc;                 // e = cw*64+tc*16+c -> head, d = c
#pragma unroll
    for (int r = 0; r < 4; ++r) {
      int nloc = rw * 16 + 4 * g + r;
      sq[h][nloc][c] = f2bf(aq[tc][r]);  // pad rows: garbage-but-finite, outputs unused
      sk[h][nloc][c] = f2bf(ak[tc][r]);  // pad rows: aef=0 -> ak=0
      sv[h][c][nloc] = f2bf(av[tc][r]);
    }
  }
  __syncthreads();
  // re-read in fragment order, write coalesced 16B/lane; wave w covers heads 2w, 2w+1
#pragma unroll
  for (int i = 0; i < 2; ++i) {
    int h = 2 * w + i;
    size_t base = (((size_t)(b * NHEAD + h)) * 16 + nt) * 512 + lane * 8;
    s16x4 klo = *reinterpret_cast<const s16x4*>(&sk[h][c][4 * g]);
    s16x4 khi = *reinterpret_cast<const s16x4*>(&sk[h][16 + c][4 * g]);
    s16x8 kfr = { klo[0], klo[1], klo[2], klo[3], khi[0], khi[1], khi[2], khi[3] };
    *reinterpret_cast<s16x8*>(khf + base) = kfr;
    s16x4 qlo = *reinterpret_cast<const s16x4*>(&sq[h][c][4 * g]);
    s16x4 qhi = *reinterpret_cast<const s16x4*>(&sq[h][16 + c][4 * g]);
    s16x8 qfr = { qlo[0], qlo[1], qlo[2], qlo[3], qhi[0], qhi[1], qhi[2], qhi[3] };
    *reinterpret_cast<s16x8*>(qhf + base) = qfr;
    s16x4 vlo = *reinterpret_cast<const s16x4*>(&sv[h][c][4 * g]);
    s16x4 vhi = *reinterpret_cast<const s16x4*>(&sv[h][c][16 + 4 * g]);
    s16x8 vfr = { vlo[0], vlo[1], vlo[2], vlo[3], vhi[0], vhi[1], vhi[2], vhi[3] };
    *reinterpret_cast<s16x8*>(vtf + base) = vfr;
  }
}

// ---------------- K2: FUSED attn + combine + pointer-logits per (b, 32-row tile) ----------------
// 512 threads = 8 waves. Phase A: wave w = head w, both 16-row halves in one m-loop, PV in
// registers, zero Phase-A barriers; K/V/Q single 16B coalesced fragment loads, K/V 2-deep
// prefetched. Softmax denominators accumulate in f32x4 partial sums (4 independent chains);
// mask extraction via u32 shl/and. Phase C: signed-tanh formulation (no abs/copysign),
// folded scale constant. No max-subtraction anywhere.
// LDS 40448 B (smask[32][500] bf16 mask'=log2e*mask + sao[32][132], reds aliased on sao).
__global__ __launch_bounds__(512, 4) void k_fused(
    const unsigned short* __restrict__ qhf, const unsigned short* __restrict__ khf,
    const unsigned short* __restrict__ vtf, const unsigned short* __restrict__ eff,
    const unsigned short* __restrict__ wt, const float* __restrict__ bcp,
    const float* __restrict__ mask, float* __restrict__ probs) {
  int wgid = blockIdx.x;                 // 1024
  int xcd = wgid & 7;
  int s = wgid >> 3;
  int nt = s & 15;
  int b = (s >> 4) * 8 + xcd;            // all 16 tiles of b on one XCD
  int tid = threadIdx.x;
  int w = tid >> 6, lane = tid & 63, g = lane >> 4, c = lane & 15;
  int nt32 = nt * 32;

  __shared__ __align__(16) char uni[40448];
  unsigned short (*smask)[500] = reinterpret_cast<unsigned short(*)[500]>(uni);          // 32000 B
  unsigned short (*sao)[132]   = reinterpret_cast<unsigned short(*)[132]>(uni + 32000);  // 8448 B
  float (*reds)[2][16]         = reinterpret_cast<float(*)[2][16]>(uni + 32000);         // aliases sao

  const float LOG2E = 1.4426950408889634f;
  const unsigned short BFNI = f2bf(-14427.0f);
  const unsigned NIP = ((unsigned)BFNI << 16) | (unsigned)BFNI;

  // ---- stage mask' = log2e * mask as bf16, real 500 cols only ----
  for (int idx = tid; idx < 32 * 125; idx += 512) {
    int rl = idx / 125;
    int m4 = idx - rl * 125;
    int nr = nt32 + rl;
    f32x4 v = {0.f, 0.f, 0.f, 0.f};
    if (nr < NN_) v = *reinterpret_cast<const f32x4*>(mask + ((size_t)b * NN_ + nr) * NN_ + m4 * 4);
    unsigned lo = cvtpk(v[0] * LOG2E, v[1] * LOG2E);
    unsigned hi = cvtpk(v[2] * LOG2E, v[3] * LOG2E);
    *reinterpret_cast<uint2*>(&smask[rl][m4 * 4]) = make_uint2(lo, hi);
  }
  __syncthreads();                        // S1: smask visible

  // ================= Phase A: attention, wave w = head w, zero barriers =================
  {
    int h = w;
    const unsigned short* qf = qhf + ((((size_t)(b * NHEAD + h)) * 16 + nt)) * 512 + lane * 8;
    const unsigned short* kf_base = khf + (((size_t)(b * NHEAD + h)) * 16) * 512 + lane * 8;
    const unsigned short* vf_base = vtf + (((size_t)(b * NHEAD + h)) * 16) * 512 + lane * 8;

    s16x8 qv = *reinterpret_cast<const s16x8*>(qf);
    s16x8 bq0 = { qv[0], qv[1], qv[2], qv[3], 0, 0, 0, 0 };
    s16x8 bq1 = { qv[4], qv[5], qv[6], qv[7], 0, 0, 0, 0 };

    f32x4 o0 = {0,0,0,0}, o1 = {0,0,0,0};
    f32x4 lsa = {0,0,0,0}, lsb = {0,0,0,0};

    // 2-deep prefetch of the coalesced K/V fragment loads
    s16x8 kvA = *reinterpret_cast<const s16x8*>(kf_base);
    s16x8 vvA = *reinterpret_cast<const s16x8*>(vf_base);
    s16x8 kvB = *reinterpret_cast<const s16x8*>(kf_base + 512);
    s16x8 vvB = *reinterpret_cast<const s16x8*>(vf_base + 512);

    for (int mt = 0; mt < 16; ++mt) {
      int m0 = mt * 32;
      s16x8 kv = kvA, af = vvA;
      kvA = kvB; vvA = vvB;
      if (mt < 14) {
        kvB = *reinterpret_cast<const s16x8*>(kf_base + (mt + 2) * 512);
        vvB = *reinterpret_cast<const s16x8*>(vf_base + (mt + 2) * 512);
      }
      s16x8 kf0 = { kv[0], kv[1], kv[2], kv[3], 0, 0, 0, 0 };
      s16x8 kf1 = { kv[4], kv[5], kv[6], kv[7], 0, 0, 0, 0 };
      uint2 u00 = *reinterpret_cast<const uint2*>(&smask[c][m0 + 4 * g]);
      uint2 u10 = *reinterpret_cast<const uint2*>(&smask[16 + c][m0 + 4 * g]);
      uint2 u01, u11;
      if (mt < 15 || g == 0) {
        u01 = *reinterpret_cast<const uint2*>(&smask[c][m0 + 16 + 4 * g]);
        u11 = *reinterpret_cast<const uint2*>(&smask[16 + c][m0 + 16 + 4 * g]);
      } else {
        u01 = make_uint2(NIP, NIP);
        u11 = u01;
      }
      f32x4 a0 = MFMA(kf0, bq0, (f32x4){0,0,0,0});
      f32x4 a1 = MFMA(kf1, bq0, (f32x4){0,0,0,0});
      f32x4 b0 = MFMA(kf0, bq1, (f32x4){0,0,0,0});
      f32x4 b1 = MFMA(kf1, bq1, (f32x4){0,0,0,0});
      const float S = 0.36067376022224085f;  // 0.25 * log2e
      a0[0] = EXP2(fmaf(a0[0], S, blo(u00.x)));
      a0[1] = EXP2(fmaf(a0[1], S, bhi(u00.x)));
      a0[2] = EXP2(fmaf(a0[2], S, blo(u00.y)));
      a0[3] = EXP2(fmaf(a0[3], S, bhi(u00.y)));
      a1[0] = EXP2(fmaf(a1[0], S, blo(u01.x)));
      a1[1] = EXP2(fmaf(a1[1], S, bhi(u01.x)));
      a1[2] = EXP2(fmaf(a1[2], S, blo(u01.y)));
      a1[3] = EXP2(fmaf(a1[3], S, bhi(u01.y)));
      b0[0] = EXP2(fmaf(b0[0], S, blo(u10.x)));
      b0[1] = EXP2(fmaf(b0[1], S, bhi(u10.x)));
      b0[2] = EXP2(fmaf(b0[2], S, blo(u10.y)));
      b0[3] = EXP2(fmaf(b0[3], S, bhi(u10.y)));
      b1[0] = EXP2(fmaf(b1[0], S, blo(u11.x)));
      b1[1] = EXP2(fmaf(b1[1], S, bhi(u11.x)));
      b1[2] = EXP2(fmaf(b1[2], S, blo(u11.y)));
      b1[3] = EXP2(fmaf(b1[3], S, bhi(u11.y)));
      lsa += a0; lsa += a1;
      lsb += b0; lsb += b1;
      o0 = MFMA(af, pack8_m(a0, a1), o0);  // s_nop-hardened packs feed MFMA SrcB
      o1 = MFMA(af, pack8_m(b0, b1), o1);
    }
    float ls0 = (lsa[0] + lsa[1]) + (lsa[2] + lsa[3]);
    float ls1 = (lsb[0] + lsb[1]) + (lsb[2] + lsb[3]);
    ls0 += __shfl_xor(ls0, 16);
    ls0 += __shfl_xor(ls0, 32);
    ls1 += __shfl_xor(ls1, 16);
    ls1 += __shfl_xor(ls1, 32);
    float inv0 = RCP(ls0), inv1 = RCP(ls1);
    *reinterpret_cast<uint2*>(&sao[c][w * HD + 4 * g]) =
        make_uint2(cvtpk(o0[0] * inv0, o0[1] * inv0), cvtpk(o0[2] * inv0, o0[3] * inv0));
    *reinterpret_cast<uint2*>(&sao[16 + c][w * HD + 4 * g]) =
        make_uint2(cvtpk(o1[0] * inv1, o1[1] * inv1), cvtpk(o1[2] * inv1, o1[3] * inv1));
  }
  __syncthreads();                        // A1: sao (ao tile) complete

  // ================= Phase B: mh = ao @ Wc + bc =================
  int mw = w & 3, nw = w >> 2;
  float bias0 = bcp[mw * 32 + c];
  float bias1 = bcp[mw * 32 + 16 + c];
  f32x4 acm0 = {0,0,0,0}, acm1 = {0,0,0,0};
#pragma unroll
  for (int kk = 0; kk < 4; ++kk) {
    int k0 = kk * 32 + 8 * g;
    s16x8 aa = *reinterpret_cast<const s16x8*>(&sao[nw * 16 + c][k0]);
    s16x8 bw0 = *reinterpret_cast<const s16x8*>(wt + 4 * 16384 + (mw * 32 + c) * EE + k0);
    s16x8 bw1 = *reinterpret_cast<const s16x8*>(wt + 4 * 16384 + (mw * 32 + 16 + c) * EE + k0);
    acm0 = MFMA(aa, bw0, acm0);
    acm1 = MFMA(aa, bw1, acm1);
  }
  __syncthreads();                        // B1: all sao reads done
#pragma unroll
  for (int r = 0; r < 4; ++r) {
    sao[nw * 16 + 4 * g + r][mw * 32 + c]      = f2bf(acm0[r] + bias0);
    sao[nw * 16 + 4 * g + r][mw * 32 + 16 + c] = f2bf(acm1[r] + bias1);
  }
  __syncthreads();                        // B2: mh tile ready

  // ================= Phase C: pointer logits + softmax (signed tanh; no max-sub) =====
  f32x4 sc[8];
#pragma unroll
  for (int t = 0; t < 8; ++t) sc[t] = (f32x4){0,0,0,0};
#pragma unroll
  for (int kk = 0; kk < 4; ++kk) {
    int k0 = kk * 32 + 8 * g;
    s16x8 am = *reinterpret_cast<const s16x8*>(&sao[nw * 16 + c][k0]);
#pragma unroll
    for (int t = 0; t < 8; ++t) {
      s16x8 bfr = *reinterpret_cast<const s16x8*>(
          eff + (((size_t)(b * 32 + mw * 8 + t)) * 4 + kk) * 512 + lane * 8);
      sc[t] = MFMA(am, bfr, sc[t]);
    }
  }
  float rsum[4] = {0, 0, 0, 0};
#pragma unroll
  for (int t = 0; t < 8; ++t) {
    int m = mw * 128 + t * 16 + c;
    bool mok = (m < NN_);
#pragma unroll
    for (int r = 0; r < 4; ++r) {
      // th = tanh(s/sqrt(128)) = 1 - 2/(e^{2s/sqrt(128)}+1); exact at both rails (rcp(inf)=0)
      float e2 = EXP2(sc[t][r] * 0.25503486f);     // 2*log2e/sqrt(128)
      float th = fmaf(-2.0f, RCP(e2 + 1.0f), 1.0f);
      float mm = mok ? bf2f(smask[nw * 16 + 4 * g + r][m]) : -14427.0f;
      float p = EXP2(fmaf(th, 14.426950408889634f, mm));
      sc[t][r] = p;                                 // m>=500 -> p = 0
      rsum[r] += p;
    }
  }
#pragma unroll
  for (int r = 0; r < 4; ++r) {
    rsum[r] += __shfl_xor(rsum[r], 1);
    rsum[r] += __shfl_xor(rsum[r], 2);
    rsum[r] += __shfl_xor(rsum[r], 4);
    rsum[r] += __shfl_xor(rsum[r], 8);
  }
  __syncthreads();                        // C0: sao fully dead; reds may overwrite it
  if (c == 0) {
#pragma unroll
    for (int r = 0; r < 4; ++r) reds[mw][nw][4 * g + r] = rsum[r];
  }
  __syncthreads();                        // C1
  float inv[4];
#pragma unroll
  for (int r = 0; r < 4; ++r) {
    int rr = 4 * g + r;
    inv[r] = RCP(reds[0][nw][rr] + reds[1][nw][rr] + reds[2][nw][rr] + reds[3][nw][rr]);
  }
#pragma unroll
  for (int t = 0; t < 8; ++t) {
    int m = mw * 128 + t * 16 + c;
    if (m < NN_) {
#pragma unroll
      for (int r = 0; r < 4; ++r) {
        int ng = nt32 + nw * 16 + 4 * g + r;
        if (ng < NN_) probs[((size_t)b * NN_ + ng) * NN_ + m] = sc[t][r] * inv[r];
      }
    }
  }
}

extern "C" void kernel_launch(void* const* d_in, const int* in_sizes, int n_in,
                              void* d_out, int out_size, void* d_ws, size_t ws_size,
                              hipStream_t stream) {
  const float* ef   = (const float*)d_in[0];
  const float* eq1  = (const float*)d_in[1];
  const float* eq0  = (const float*)d_in[2];
  const float* mask = (const float*)d_in[3];
  const float* wq1  = (const float*)d_in[4];
  const float* wq0  = (const float*)d_in[5];
  const float* wk   = (const float*)d_in[6];
  const float* wv   = (const float*)d_in[7];
  const float* wc   = (const float*)d_in[8];
  const float* bc   = (const float*)d_in[9];
  float* probs = (float*)d_out;

  char* ws = (char*)d_ws;
  const size_t SL = 8388608;  // 8 MB slots
  unsigned short* qhf = (unsigned short*)(ws);
  unsigned short* khf = (unsigned short*)(ws + 1 * SL);
  unsigned short* vtf = (unsigned short*)(ws + 2 * SL);
  unsigned short* eff = (unsigned short*)(ws + 3 * SL);
  unsigned short* wt  = (unsigned short*)(ws + 4 * SL);

  k_conv_w<<<80, 256, 0, stream>>>(wq1, wq0, wk, wv, wc, wt);
  k_proj<<<1024, 256, 0, stream>>>(ef, eq1, eq0, wt, qhf, khf, vtf, eff);
  k_fused<<<1024, 512, 0, stream>>>(qhf, khf, vtf, eff, wt, bc, mask, probs);
}

// Round 12
// 98.146 us; speedup vs baseline: 1.8786x; 1.1890x over previous
//
#include <hip/hip_runtime.h>
#include <hip/hip_bf16.h>
#include <cstdint>

#define BB 64
#define NN_ 500
#define NP 512
#define EE 128
#define NHEAD 8
#define HD 16

typedef float f32x4 __attribute__((ext_vector_type(4)));
typedef unsigned u32x4 __attribute__((ext_vector_type(4)));
typedef short s16x8 __attribute__((ext_vector_type(8)));
typedef short s16x4 __attribute__((ext_vector_type(4)));

__device__ __forceinline__ unsigned short f2bf(float f) {
  unsigned u = __builtin_bit_cast(unsigned, f);
  u += 0x7FFFu + ((u >> 16) & 1u);
  return (unsigned short)(u >> 16);
}

__device__ __forceinline__ float bf2f(unsigned short u) {
  unsigned v = ((unsigned)u) << 16;
  return __builtin_bit_cast(float, v);
}

__device__ __forceinline__ float blo(unsigned u) {            // low bf16 of a u32 -> f32
  return __builtin_bit_cast(float, u << 16);
}
__device__ __forceinline__ float bhi(unsigned u) {            // high bf16 of a u32 -> f32
  return __builtin_bit_cast(float, u & 0xFFFF0000u);
}

__device__ __forceinline__ unsigned cvtpk(float a, float b) {
  unsigned r;
  asm("v_cvt_pk_bf16_f32 %0, %1, %2" : "=v"(r) : "v"(a), "v"(b));
  return r;
}

// cvtpk whose result feeds an MFMA operand: pad 2 wait-states inside the asm so the
// VALU-write -> MFMA-read distance is guaranteed independent of scheduling.
__device__ __forceinline__ unsigned cvtpk_m(float a, float b) {
  unsigned r;
  asm("v_cvt_pk_bf16_f32 %0, %1, %2\n\ts_nop 1" : "=v"(r) : "v"(a), "v"(b));
  return r;
}

__device__ __forceinline__ float EXP2(float x) {
  float r;
  asm("v_exp_f32 %0, %1" : "=v"(r) : "v"(x));
  return r;
}

__device__ __forceinline__ float RCP(float x) {
  float r;
  asm("v_rcp_f32 %0, %1" : "=v"(r) : "v"(x));
  return r;
}

__device__ __forceinline__ s16x8 pack8(f32x4 a, f32x4 b) {
  u32x4 u = { cvtpk(a[0], a[1]), cvtpk(a[2], a[3]), cvtpk(b[0], b[1]), cvtpk(b[2], b[3]) };
  return __builtin_bit_cast(s16x8, u);
}

__device__ __forceinline__ s16x8 pack8_m(f32x4 a, f32x4 b) {
  u32x4 u = { cvtpk_m(a[0], a[1]), cvtpk_m(a[2], a[3]), cvtpk_m(b[0], b[1]), cvtpk_m(b[2], b[3]) };
  return __builtin_bit_cast(s16x8, u);
}

__device__ __forceinline__ f32x4 MFMA(s16x8 a, s16x8 b, f32x4 c) {
  return __builtin_amdgcn_mfma_f32_16x16x32_bf16(a, b, c, 0, 0, 0);
}

// ---------------- K0b: W^T -> wtf in MFMA-fragment lane order ----------------
// wtf[((mat*8 + etile)*4 + kk)*512 + lane*8 + j] = W_mat^T[etile*16+c][kk*32+8g+j]
//   (lane = (g,c));  B-operand loads in k_proj / k_fused Phase B become 16B coalesced.
__global__ void k_conv_w(const float* __restrict__ w0, const float* __restrict__ w1,
                         const float* __restrict__ w2, const float* __restrict__ w3,
                         const float* __restrict__ w4, unsigned short* __restrict__ wtf) {
  int t = blockIdx.x * 256 + threadIdx.x;     // 5*8*4*64 = 10240
  int lane = t & 63;
  int kk = (t >> 6) & 3;
  int etile = (t >> 8) & 7;
  int m = t >> 11;                            // 0..4
  const float* w = (m == 0) ? w0 : (m == 1) ? w1 : (m == 2) ? w2 : (m == 3) ? w3 : w4;
  int g = lane >> 4, c = lane & 15;
  int e = etile * 16 + c;
  int k0 = kk * 32 + 8 * g;
  f32x4 A, B;
#pragma unroll
  for (int j = 0; j < 4; ++j) A[j] = w[(k0 + j) * 128 + e];       // W^T[e][k] = w[k][e]
#pragma unroll
  for (int j = 0; j < 4; ++j) B[j] = w[(k0 + 4 + j) * 128 + e];
  *reinterpret_cast<s16x8*>(wtf + (((m * 8 + etile) * 4 + kk) * 512) + lane * 8) = pack8(A, B);
}

// ---------------- K1: projections -> qhf/khf/vtf/eff ALL in MFMA-fragment lane order ----------
// qhf/khf[b][h][nt/mt][lane]: {X[t0+c][4g..4g+3], X[t0+16+c][4g..4g+3]}  (16B/lane coalesced)
// vtf[b][h][mt][lane]:        {V[m0+4g..+3][c],   V[m0+16+4g..+3][c]}    (= PV A-fragment)
// eff[b][rt][kk][lane]:       ef[rt*16+c][kk*32+8g..+7]                  (= Phase-C B-fragment)
// Q/K/V go through a small LDS transpose; eff is a direct register store. 1-deep prefetch on
// the six input float4 loads across the kk loop. ALL weight loads now coalesced via wtf.
__global__ __launch_bounds__(256) void k_proj(
    const float* __restrict__ ef,
    const float* __restrict__ eq1, const float* __restrict__ eq0,
    const unsigned short* __restrict__ wtf,
    unsigned short* __restrict__ qhf, unsigned short* __restrict__ khf,
    unsigned short* __restrict__ vtf, unsigned short* __restrict__ eff) {
  int wgid = blockIdx.x;                 // 1024
  int xcd = wgid & 7;
  int s = wgid >> 3;
  int nt = s & 15;
  int b = (s >> 4) * 8 + xcd;
  int tid = threadIdx.x;
  int w = tid >> 6, lane = tid & 63, g = lane >> 4, c = lane & 15;
  int rw = w & 1, cw = w >> 1;
  int nbase = nt * 32 + rw * 16;

  __shared__ unsigned short sk[8][32][20];   // 10240 B
  __shared__ unsigned short sv[8][16][36];   // 9216 B
  __shared__ unsigned short sq[8][32][20];   // 10240 B -> 29696 B total

  f32x4 ak[4], av[4], aq[4];
#pragma unroll
  for (int t = 0; t < 4; ++t) { ak[t]=(f32x4){0,0,0,0}; av[t]=(f32x4){0,0,0,0}; aq[t]=(f32x4){0,0,0,0}; }

  int nA = nbase + c;
  int nc = nA < NN_ ? nA : NN_ - 1;
  bool val = (nA < NN_);

  const float* pe_base = ef  + ((size_t)(b * NN_ + nc)) * EE;
  const float* p1_base = eq1 + ((size_t)(b * NN_ + nc)) * EE;
  const float* p0_base = eq0 + ((size_t)(b * NN_ + nc)) * EE;

  // prefetch kk = 0
  int k0p = 8 * g;
  f32x4 eA  = *reinterpret_cast<const f32x4*>(pe_base + k0p);
  f32x4 eB  = *reinterpret_cast<const f32x4*>(pe_base + k0p + 4);
  f32x4 u1A = *reinterpret_cast<const f32x4*>(p1_base + k0p);
  f32x4 u1B = *reinterpret_cast<const f32x4*>(p1_base + k0p + 4);
  f32x4 u0A = *reinterpret_cast<const f32x4*>(p0_base + k0p);
  f32x4 u0B = *reinterpret_cast<const f32x4*>(p0_base + k0p + 4);

  for (int kk = 0; kk < 4; ++kk) {
    s16x8 aef = {0,0,0,0,0,0,0,0};
    if (val) aef = pack8(eA, eB);
    s16x8 a1 = pack8(u1A, u1B);
    s16x8 a0 = pack8(u0A, u0B);
    if (kk < 3) {                         // prefetch kk+1
      int kn = (kk + 1) * 32 + 8 * g;
      eA  = *reinterpret_cast<const f32x4*>(pe_base + kn);
      eB  = *reinterpret_cast<const f32x4*>(pe_base + kn + 4);
      u1A = *reinterpret_cast<const f32x4*>(p1_base + kn);
      u1B = *reinterpret_cast<const f32x4*>(p1_base + kn + 4);
      u0A = *reinterpret_cast<const f32x4*>(p0_base + kn);
      u0B = *reinterpret_cast<const f32x4*>(p0_base + kn + 4);
    }
    if (cw == 0)                          // eff: direct fragment store, coalesced 16B/lane
      *reinterpret_cast<s16x8*>(eff + (((size_t)(b * 32 + 2 * nt + rw)) * 4 + kk) * 512 + lane * 8) = aef;
#pragma unroll
    for (int tc = 0; tc < 4; ++tc) {
      int et = cw * 4 + tc;               // etile; e = et*16 + c
      const unsigned short* wf = wtf + lane * 8 + (size_t)kk * 512;
      s16x8 bq1 = *reinterpret_cast<const s16x8*>(wf + ((0 * 8 + et) * 4) * 512);
      s16x8 bq0 = *reinterpret_cast<const s16x8*>(wf + ((1 * 8 + et) * 4) * 512);
      s16x8 bk  = *reinterpret_cast<const s16x8*>(wf + ((2 * 8 + et) * 4) * 512);
      s16x8 bv  = *reinterpret_cast<const s16x8*>(wf + ((3 * 8 + et) * 4) * 512);
      ak[tc] = MFMA(aef, bk, ak[tc]);
      av[tc] = MFMA(aef, bv, av[tc]);
      aq[tc] = MFMA(a1, bq1, aq[tc]);
      aq[tc] = MFMA(a0, bq0, aq[tc]);
    }
  }
#pragma unroll
  for (int tc = 0; tc < 4; ++tc) {
    int h = cw * 4 + tc;                 // e = cw*64+tc*16+c -> head, d = c
#pragma unroll
    for (int r = 0; r < 4; ++r) {
      int nloc = rw * 16 + 4 * g + r;
      sq[h][nloc][c] = f2bf(aq[tc][r]);  // pad rows: garbage-but-finite, outputs unused
      sk[h][nloc][c] = f2bf(ak[tc][r]);  // pad rows: aef=0 -> ak=0
      sv[h][c][nloc] = f2bf(av[tc][r]);
    }
  }
  __syncthreads();
  // re-read in fragment order, write coalesced 16B/lane; wave w covers heads 2w, 2w+1
#pragma unroll
  for (int i = 0; i < 2; ++i) {
    int h = 2 * w + i;
    size_t base = (((size_t)(b * NHEAD + h)) * 16 + nt) * 512 + lane * 8;
    s16x4 klo = *reinterpret_cast<const s16x4*>(&sk[h][c][4 * g]);
    s16x4 khi = *reinterpret_cast<const s16x4*>(&sk[h][16 + c][4 * g]);
    s16x8 kfr = { klo[0], klo[1], klo[2], klo[3], khi[0], khi[1], khi[2], khi[3] };
    *reinterpret_cast<s16x8*>(khf + base) = kfr;
    s16x4 qlo = *reinterpret_cast<const s16x4*>(&sq[h][c][4 * g]);
    s16x4 qhi = *reinterpret_cast<const s16x4*>(&sq[h][16 + c][4 * g]);
    s16x8 qfr = { qlo[0], qlo[1], qlo[2], qlo[3], qhi[0], qhi[1], qhi[2], qhi[3] };
    *reinterpret_cast<s16x8*>(qhf + base) = qfr;
    s16x4 vlo = *reinterpret_cast<const s16x4*>(&sv[h][c][4 * g]);
    s16x4 vhi = *reinterpret_cast<const s16x4*>(&sv[h][c][16 + 4 * g]);
    s16x8 vfr = { vlo[0], vlo[1], vlo[2], vlo[3], vhi[0], vhi[1], vhi[2], vhi[3] };
    *reinterpret_cast<s16x8*>(vtf + base) = vfr;
  }
}

// ---------------- K2: FUSED attn + combine + pointer-logits per (b, 32-row tile) ----------------
// 512 threads = 8 waves. Phase A: wave w = head w, both 16-row halves in one m-loop, PV in
// registers, zero Phase-A barriers; K/V/Q single 16B coalesced fragment loads, K/V 2-deep
// prefetched. Phase B weight loads coalesced via wtf. Phase C: signed-tanh formulation.
// No max-subtraction anywhere. LDS 40448 B (smask[32][500] + sao[32][132], reds aliased).
__global__ __launch_bounds__(512, 4) void k_fused(
    const unsigned short* __restrict__ qhf, const unsigned short* __restrict__ khf,
    const unsigned short* __restrict__ vtf, const unsigned short* __restrict__ eff,
    const unsigned short* __restrict__ wtf, const float* __restrict__ bcp,
    const float* __restrict__ mask, float* __restrict__ probs) {
  int wgid = blockIdx.x;                 // 1024
  int xcd = wgid & 7;
  int s = wgid >> 3;
  int nt = s & 15;
  int b = (s >> 4) * 8 + xcd;            // all 16 tiles of b on one XCD
  int tid = threadIdx.x;
  int w = tid >> 6, lane = tid & 63, g = lane >> 4, c = lane & 15;
  int nt32 = nt * 32;

  __shared__ __align__(16) char uni[40448];
  unsigned short (*smask)[500] = reinterpret_cast<unsigned short(*)[500]>(uni);          // 32000 B
  unsigned short (*sao)[132]   = reinterpret_cast<unsigned short(*)[132]>(uni + 32000);  // 8448 B
  float (*reds)[2][16]         = reinterpret_cast<float(*)[2][16]>(uni + 32000);         // aliases sao

  const float LOG2E = 1.4426950408889634f;
  const unsigned short BFNI = f2bf(-14427.0f);
  const unsigned NIP = ((unsigned)BFNI << 16) | (unsigned)BFNI;

  // ---- stage mask' = log2e * mask as bf16, real 500 cols only ----
  for (int idx = tid; idx < 32 * 125; idx += 512) {
    int rl = idx / 125;
    int m4 = idx - rl * 125;
    int nr = nt32 + rl;
    f32x4 v = {0.f, 0.f, 0.f, 0.f};
    if (nr < NN_) v = *reinterpret_cast<const f32x4*>(mask + ((size_t)b * NN_ + nr) * NN_ + m4 * 4);
    unsigned lo = cvtpk(v[0] * LOG2E, v[1] * LOG2E);
    unsigned hi = cvtpk(v[2] * LOG2E, v[3] * LOG2E);
    *reinterpret_cast<uint2*>(&smask[rl][m4 * 4]) = make_uint2(lo, hi);
  }
  __syncthreads();                        // S1: smask visible

  // ================= Phase A: attention, wave w = head w, zero barriers =================
  {
    int h = w;
    const unsigned short* qf = qhf + ((((size_t)(b * NHEAD + h)) * 16 + nt)) * 512 + lane * 8;
    const unsigned short* kf_base = khf + (((size_t)(b * NHEAD + h)) * 16) * 512 + lane * 8;
    const unsigned short* vf_base = vtf + (((size_t)(b * NHEAD + h)) * 16) * 512 + lane * 8;

    s16x8 qv = *reinterpret_cast<const s16x8*>(qf);
    s16x8 bq0 = { qv[0], qv[1], qv[2], qv[3], 0, 0, 0, 0 };
    s16x8 bq1 = { qv[4], qv[5], qv[6], qv[7], 0, 0, 0, 0 };

    f32x4 o0 = {0,0,0,0}, o1 = {0,0,0,0};
    f32x4 lsa = {0,0,0,0}, lsb = {0,0,0,0};

    // 2-deep prefetch of the coalesced K/V fragment loads
    s16x8 kvA = *reinterpret_cast<const s16x8*>(kf_base);
    s16x8 vvA = *reinterpret_cast<const s16x8*>(vf_base);
    s16x8 kvB = *reinterpret_cast<const s16x8*>(kf_base + 512);
    s16x8 vvB = *reinterpret_cast<const s16x8*>(vf_base + 512);

    for (int mt = 0; mt < 16; ++mt) {
      int m0 = mt * 32;
      s16x8 kv = kvA, af = vvA;
      kvA = kvB; vvA = vvB;
      if (mt < 14) {
        kvB = *reinterpret_cast<const s16x8*>(kf_base + (mt + 2) * 512);
        vvB = *reinterpret_cast<const s16x8*>(vf_base + (mt + 2) * 512);
      }
      s16x8 kf0 = { kv[0], kv[1], kv[2], kv[3], 0, 0, 0, 0 };
      s16x8 kf1 = { kv[4], kv[5], kv[6], kv[7], 0, 0, 0, 0 };
      uint2 u00 = *reinterpret_cast<const uint2*>(&smask[c][m0 + 4 * g]);
      uint2 u10 = *reinterpret_cast<const uint2*>(&smask[16 + c][m0 + 4 * g]);
      uint2 u01, u11;
      if (mt < 15 || g == 0) {
        u01 = *reinterpret_cast<const uint2*>(&smask[c][m0 + 16 + 4 * g]);
        u11 = *reinterpret_cast<const uint2*>(&smask[16 + c][m0 + 16 + 4 * g]);
      } else {
        u01 = make_uint2(NIP, NIP);
        u11 = u01;
      }
      f32x4 a0 = MFMA(kf0, bq0, (f32x4){0,0,0,0});
      f32x4 a1 = MFMA(kf1, bq0, (f32x4){0,0,0,0});
      f32x4 b0 = MFMA(kf0, bq1, (f32x4){0,0,0,0});
      f32x4 b1 = MFMA(kf1, bq1, (f32x4){0,0,0,0});
      const float S = 0.36067376022224085f;  // 0.25 * log2e
      a0[0] = EXP2(fmaf(a0[0], S, blo(u00.x)));
      a0[1] = EXP2(fmaf(a0[1], S, bhi(u00.x)));
      a0[2] = EXP2(fmaf(a0[2], S, blo(u00.y)));
      a0[3] = EXP2(fmaf(a0[3], S, bhi(u00.y)));
      a1[0] = EXP2(fmaf(a1[0], S, blo(u01.x)));
      a1[1] = EXP2(fmaf(a1[1], S, bhi(u01.x)));
      a1[2] = EXP2(fmaf(a1[2], S, blo(u01.y)));
      a1[3] = EXP2(fmaf(a1[3], S, bhi(u01.y)));
      b0[0] = EXP2(fmaf(b0[0], S, blo(u10.x)));
      b0[1] = EXP2(fmaf(b0[1], S, bhi(u10.x)));
      b0[2] = EXP2(fmaf(b0[2], S, blo(u10.y)));
      b0[3] = EXP2(fmaf(b0[3], S, bhi(u10.y)));
      b1[0] = EXP2(fmaf(b1[0], S, blo(u11.x)));
      b1[1] = EXP2(fmaf(b1[1], S, bhi(u11.x)));
      b1[2] = EXP2(fmaf(b1[2], S, blo(u11.y)));
      b1[3] = EXP2(fmaf(b1[3], S, bhi(u11.y)));
      lsa += a0; lsa += a1;
      lsb += b0; lsb += b1;
      o0 = MFMA(af, pack8_m(a0, a1), o0);  // s_nop-hardened packs feed MFMA SrcB
      o1 = MFMA(af, pack8_m(b0, b1), o1);
    }
    float ls0 = (lsa[0] + lsa[1]) + (lsa[2] + lsa[3]);
    float ls1 = (lsb[0] + lsb[1]) + (lsb[2] + lsb[3]);
    ls0 += __shfl_xor(ls0, 16);
    ls0 += __shfl_xor(ls0, 32);
    ls1 += __shfl_xor(ls1, 16);
    ls1 += __shfl_xor(ls1, 32);
    float inv0 = RCP(ls0), inv1 = RCP(ls1);
    *reinterpret_cast<uint2*>(&sao[c][w * HD + 4 * g]) =
        make_uint2(cvtpk(o0[0] * inv0, o0[1] * inv0), cvtpk(o0[2] * inv0, o0[3] * inv0));
    *reinterpret_cast<uint2*>(&sao[16 + c][w * HD + 4 * g]) =
        make_uint2(cvtpk(o1[0] * inv1, o1[1] * inv1), cvtpk(o1[2] * inv1, o1[3] * inv1));
  }
  __syncthreads();                        // A1: sao (ao tile) complete

  // ================= Phase B: mh = ao @ Wc + bc =================
  int mw = w & 3, nw = w >> 2;
  float bias0 = bcp[mw * 32 + c];
  float bias1 = bcp[mw * 32 + 16 + c];
  f32x4 acm0 = {0,0,0,0}, acm1 = {0,0,0,0};
#pragma unroll
  for (int kk = 0; kk < 4; ++kk) {
    int k0 = kk * 32 + 8 * g;
    s16x8 aa = *reinterpret_cast<const s16x8*>(&sao[nw * 16 + c][k0]);
    s16x8 bw0 = *reinterpret_cast<const s16x8*>(wtf + (((4 * 8 + mw * 2 + 0) * 4 + kk) * 512) + lane * 8);
    s16x8 bw1 = *reinterpret_cast<const s16x8*>(wtf + (((4 * 8 + mw * 2 + 1) * 4 + kk) * 512) + lane * 8);
    acm0 = MFMA(aa, bw0, acm0);
    acm1 = MFMA(aa, bw1, acm1);
  }
  __syncthreads();                        // B1: all sao reads done
#pragma unroll
  for (int r = 0; r < 4; ++r) {
    sao[nw * 16 + 4 * g + r][mw * 32 + c]      = f2bf(acm0[r] + bias0);
    sao[nw * 16 + 4 * g + r][mw * 32 + 16 + c] = f2bf(acm1[r] + bias1);
  }
  __syncthreads();                        // B2: mh tile ready

  // ================= Phase C: pointer logits + softmax (signed tanh; no max-sub) =====
  f32x4 sc[8];
#pragma unroll
  for (int t = 0; t < 8; ++t) sc[t] = (f32x4){0,0,0,0};
#pragma unroll
  for (int kk = 0; kk < 4; ++kk) {
    int k0 = kk * 32 + 8 * g;
    s16x8 am = *reinterpret_cast<const s16x8*>(&sao[nw * 16 + c][k0]);
#pragma unroll
    for (int t = 0; t < 8; ++t) {
      s16x8 bfr = *reinterpret_cast<const s16x8*>(
          eff + (((size_t)(b * 32 + mw * 8 + t)) * 4 + kk) * 512 + lane * 8);
      sc[t] = MFMA(am, bfr, sc[t]);
    }
  }
  float rsum[4] = {0, 0, 0, 0};
#pragma unroll
  for (int t = 0; t < 8; ++t) {
    int m = mw * 128 + t * 16 + c;
    bool mok = (m < NN_);
#pragma unroll
    for (int r = 0; r < 4; ++r) {
      // th = tanh(s/sqrt(128)) = 1 - 2/(e^{2s/sqrt(128)}+1); exact at both rails (rcp(inf)=0)
      float e2 = EXP2(sc[t][r] * 0.25503486f);     // 2*log2e/sqrt(128)
      float th = fmaf(-2.0f, RCP(e2 + 1.0f), 1.0f);
      float mm = mok ? bf2f(smask[nw * 16 + 4 * g + r][m]) : -14427.0f;
      float p = EXP2(fmaf(th, 14.426950408889634f, mm));
      sc[t][r] = p;                                 // m>=500 -> p = 0
      rsum[r] += p;
    }
  }
#pragma unroll
  for (int r = 0; r < 4; ++r) {
    rsum[r] += __shfl_xor(rsum[r], 1);
    rsum[r] += __shfl_xor(rsum[r], 2);
    rsum[r] += __shfl_xor(rsum[r], 4);
    rsum[r] += __shfl_xor(rsum[r], 8);
  }
  __syncthreads();                        // C0: sao fully dead; reds may overwrite it
  if (c == 0) {
#pragma unroll
    for (int r = 0; r < 4; ++r) reds[mw][nw][4 * g + r] = rsum[r];
  }
  __syncthreads();                        // C1
  float inv[4];
#pragma unroll
  for (int r = 0; r < 4; ++r) {
    int rr = 4 * g + r;
    inv[r] = RCP(reds[0][nw][rr] + reds[1][nw][rr] + reds[2][nw][rr] + reds[3][nw][rr]);
  }
#pragma unroll
  for (int t = 0; t < 8; ++t) {
    int m = mw * 128 + t * 16 + c;
    if (m < NN_) {
#pragma unroll
      for (int r = 0; r < 4; ++r) {
        int ng = nt32 + nw * 16 + 4 * g + r;
        if (ng < NN_) probs[((size_t)b * NN_ + ng) * NN_ + m] = sc[t][r] * inv[r];
      }
    }
  }
}

extern "C" void kernel_launch(void* const* d_in, const int* in_sizes, int n_in,
                              void* d_out, int out_size, void* d_ws, size_t ws_size,
                              hipStream_t stream) {
  const float* ef   = (const float*)d_in[0];
  const float* eq1  = (const float*)d_in[1];
  const float* eq0  = (const float*)d_in[2];
  const float* mask = (const float*)d_in[3];
  const float* wq1  = (const float*)d_in[4];
  const float* wq0  = (const float*)d_in[5];
  const float* wk   = (const float*)d_in[6];
  const float* wv   = (const float*)d_in[7];
  const float* wc   = (const float*)d_in[8];
  const float* bc   = (const float*)d_in[9];
  float* probs = (float*)d_out;

  char* ws = (char*)d_ws;
  const size_t SL = 8388608;  // 8 MB slots
  unsigned short* qhf = (unsigned short*)(ws);
  unsigned short* khf = (unsigned short*)(ws + 1 * SL);
  unsigned short* vtf = (unsigned short*)(ws + 2 * SL);
  unsigned short* eff = (unsigned short*)(ws + 3 * SL);
  unsigned short* wtf = (unsigned short*)(ws + 4 * SL);

  k_conv_w<<<40, 256, 0, stream>>>(wq1, wq0, wk, wv, wc, wtf);
  k_proj<<<1024, 256, 0, stream>>>(ef, eq1, eq0, wtf, qhf, khf, vtf, eff);
  k_fused<<<1024, 512, 0, stream>>>(qhf, khf, vtf, eff, wtf, bc, mask, probs);
}